// Round 1
// baseline (4992.408 us; speedup 1.0000x reference)
//
#include <hip/hip_runtime.h>
#include <stdint.h>

// ============================================================================
// Bit-exact replication of the JAX reference Gibbs sampler.
// Semantics flag: modern JAX (>=0.5.0) defaults jax_threefry_partitionable=True.
//   R1 ships PARTITIONABLE=1. If absmax=1.0, flip to 0 (classic) next round.
// ============================================================================
#define JAX_PARTITIONABLE 1

#define MIX_TIME 20
#define NCHAIN   16384   // S*B = 128*128
#define DDIM     512
#define CHAINS_PER_BLOCK 16

struct U2 { uint32_t a, b; };

__device__ __forceinline__ uint32_t rotl32(uint32_t v, int r) {
  return (v << r) | (v >> (32 - r));
}

// Threefry-2x32, 20 rounds (JAX prng.py / Random123).
__device__ __forceinline__ U2 tf2x32(uint32_t k0, uint32_t k1, uint32_t x0, uint32_t x1) {
  const uint32_t ks2 = k0 ^ k1 ^ 0x1BD11BDAu;
  x0 += k0; x1 += k1;
  // group 0: 13,15,26,6
  x0 += x1; x1 = rotl32(x1, 13); x1 ^= x0;
  x0 += x1; x1 = rotl32(x1, 15); x1 ^= x0;
  x0 += x1; x1 = rotl32(x1, 26); x1 ^= x0;
  x0 += x1; x1 = rotl32(x1,  6); x1 ^= x0;
  x0 += k1; x1 += ks2 + 1u;
  // group 1: 17,29,16,24
  x0 += x1; x1 = rotl32(x1, 17); x1 ^= x0;
  x0 += x1; x1 = rotl32(x1, 29); x1 ^= x0;
  x0 += x1; x1 = rotl32(x1, 16); x1 ^= x0;
  x0 += x1; x1 = rotl32(x1, 24); x1 ^= x0;
  x0 += ks2; x1 += k0 + 2u;
  // group 2: 13,15,26,6
  x0 += x1; x1 = rotl32(x1, 13); x1 ^= x0;
  x0 += x1; x1 = rotl32(x1, 15); x1 ^= x0;
  x0 += x1; x1 = rotl32(x1, 26); x1 ^= x0;
  x0 += x1; x1 = rotl32(x1,  6); x1 ^= x0;
  x0 += k0; x1 += k1 + 3u;
  // group 3: 17,29,16,24
  x0 += x1; x1 = rotl32(x1, 17); x1 ^= x0;
  x0 += x1; x1 = rotl32(x1, 29); x1 ^= x0;
  x0 += x1; x1 = rotl32(x1, 16); x1 ^= x0;
  x0 += x1; x1 = rotl32(x1, 24); x1 ^= x0;
  x0 += k1; x1 += ks2 + 4u;
  // group 4: 13,15,26,6
  x0 += x1; x1 = rotl32(x1, 13); x1 ^= x0;
  x0 += x1; x1 = rotl32(x1, 15); x1 ^= x0;
  x0 += x1; x1 = rotl32(x1, 26); x1 ^= x0;
  x0 += x1; x1 = rotl32(x1,  6); x1 ^= x0;
  x0 += ks2; x1 += k0 + 5u;
  return {x0, x1};
}

// random_bits(key, 32, (size,))[m].  'half' = size/2 used by the classic path.
__device__ __forceinline__ uint32_t rbits32(uint32_t k0, uint32_t k1,
                                            uint32_t m, uint32_t half) {
#if JAX_PARTITIONABLE
  U2 r = tf2x32(k0, k1, 0u, m);
  return r.a ^ r.b;
#else
  if (m < half) { return tf2x32(k0, k1, m, half + m).a; }
  else          { return tf2x32(k0, k1, m - half, m).b; }
#endif
}

// split(key, num)[idx]
__device__ __forceinline__ U2 split_key(uint32_t k0, uint32_t k1,
                                        uint32_t idx, uint32_t num) {
#if JAX_PARTITIONABLE
  return tf2x32(k0, k1, 0u, idx);   // foldlike: child = both output words
#else
  // classic: counts 0..2n-1 halved; concat[m] = m<n ? TF(m, n+m).a : TF(m-n, m).b
  const uint32_t m0 = 2u * idx, m1 = 2u * idx + 1u;
  const uint32_t w0 = (m0 < num) ? tf2x32(k0, k1, m0, num + m0).a
                                 : tf2x32(k0, k1, m0 - num, m0).b;
  const uint32_t w1 = (m1 < num) ? tf2x32(k0, k1, m1, num + m1).a
                                 : tf2x32(k0, k1, m1 - num, m1).b;
  return {w0, w1};
#endif
}

// ============================================================================
// Kernel 1: per-step table {i, j, ks0, ks1}.  Grid: MIX_TIME blocks x 64 thr.
// ============================================================================
__global__ __launch_bounds__(64)
void gibbs_steps_kernel(uint32_t* __restrict__ tbl) {
  const uint32_t t    = blockIdx.x;
  const uint32_t lane = threadIdx.x;

  // root key = jax.random.key(1) -> (0, 1)
  const U2 K   = split_key(0u, 1u, t, (uint32_t)MIX_TIME);
  const U2 ki  = split_key(K.a, K.b, 0u, 2u);
  const U2 ks  = split_key(K.a, K.b, 1u, 2u);
  // _shuffle: key, subkey = split(ki); bits from subkey
  const U2 sub = split_key(ki.a, ki.b, 1u, 2u);

  // 512 sort keys; stable two-smallest by (key, index) lex order.
  uint32_t k1 = 0xFFFFFFFFu, m1 = 0xFFFFFFFFu;
  uint32_t k2 = 0xFFFFFFFFu, m2 = 0xFFFFFFFFu;
  #pragma unroll
  for (int p = 0; p < 8; ++p) {
    const uint32_t m   = lane + 64u * (uint32_t)p;
    const uint32_t key = rbits32(sub.a, sub.b, m, 256u);
    const bool lt1 = (key < k1) || (key == k1 && m < m1);
    const bool lt2 = (key < k2) || (key == k2 && m < m2);
    if (lt1)      { k2 = k1; m2 = m1; k1 = key; m1 = m; }
    else if (lt2) { k2 = key; m2 = m; }
  }
  // butterfly merge across 64 lanes
  #pragma unroll
  for (int msk = 1; msk < 64; msk <<= 1) {
    const uint32_t ok1 = __shfl_xor((int)k1, msk, 64);
    const uint32_t om1 = __shfl_xor((int)m1, msk, 64);
    const uint32_t ok2 = __shfl_xor((int)k2, msk, 64);
    const uint32_t om2 = __shfl_xor((int)m2, msk, 64);
    const bool oless = (ok1 < k1) || (ok1 == k1 && om1 < m1);
    if (oless) {
      const bool l2 = (k1 < ok2) || (k1 == ok2 && m1 < om2);
      const uint32_t nk2 = l2 ? k1 : ok2, nm2 = l2 ? m1 : om2;
      k1 = ok1; m1 = om1; k2 = nk2; m2 = nm2;
    } else {
      const bool l2 = (ok1 < k2) || (ok1 == k2 && om1 < m2);
      if (l2) { k2 = ok1; m2 = om1; }
    }
  }
  if (lane == 0) {
    tbl[4u * t + 0u] = m1;   // i
    tbl[4u * t + 1u] = m2;   // j
    tbl[4u * t + 2u] = ks.a;
    tbl[4u * t + 3u] = ks.b;
  }
}

// ============================================================================
// Kernel 2: the sampler.  Grid: 1024 blocks x 256 threads, 16 chains/block.
// Thread (q = tid>>4 chain-local, t15 = tid&15) owns cols {4*t15 + 64*cc + e4}
// of the chain's T-row over [A | W] (1024 cols).
// ============================================================================
__global__ __launch_bounds__(256)
void gibbs_main_kernel(const float* __restrict__ A,
                       const float* __restrict__ W,
                       const float* __restrict__ z,
                       const uint32_t* __restrict__ tbl,
                       float* __restrict__ out) {
  __shared__ __align__(16) float stage[8 * 1024];     // 8 rows of [A|W]
  __shared__ uint32_t xmask[CHAINS_PER_BLOCK][16];
  __shared__ uint32_t zmask[CHAINS_PER_BLOCK][16];

  const int tid = threadIdx.x;
  const int q   = tid >> 4;      // chain local 0..15
  const int t15 = tid & 15;
  const int h   = (t15 >= 8) ? 1 : 0;
  const uint32_t chain_g = (uint32_t)blockIdx.x * CHAINS_PER_BLOCK + (uint32_t)q;
  const uint32_t bidx    = chain_g & 127u;   // chain = s*128 + b

  // ---- init masks ----
  {
    const int w = t15;
    // x0: coords [0,64) set
    xmask[q][w] = (w < 2) ? 0xFFFFFFFFu : 0u;
    uint32_t zm = 0u;
    const float* zr = z + (size_t)bidx * DDIM + 32 * w;
    #pragma unroll 1
    for (int s = 0; s < 32; ++s)
      if (zr[s] > 0.5f) zm |= (1u << s);
    zmask[q][w] = zm;
  }
  __syncthreads();

  // z-words this thread needs (static-indexed regs)
  uint32_t zw[8];
  #pragma unroll
  for (int cc = 0; cc < 8; ++cc) zw[cc] = zmask[q][2 * cc + h];

  #pragma unroll 1
  for (int t = 0; t < MIX_TIME; ++t) {
    const uint32_t ii  = tbl[4 * t + 0];
    const uint32_t jj  = tbl[4 * t + 1];
    const uint32_t ks0 = tbl[4 * t + 2];
    const uint32_t ks1 = tbl[4 * t + 3];

    // ---- T1b/T2b: sum rows of [A|W] over d in ones(x)\{i,j}, d ascending ----
    float acc[16][4];
    #pragma unroll
    for (int cc = 0; cc < 16; ++cc) {
      acc[cc][0] = 0.f; acc[cc][1] = 0.f; acc[cc][2] = 0.f; acc[cc][3] = 0.f;
    }

    #pragma unroll 1
    for (int d0 = 0; d0 < DDIM; d0 += 8) {
      __syncthreads();
      // stage 8 rows x 1024 cols cooperatively (coalesced float4)
      #pragma unroll
      for (int p = 0; p < 8; ++p) {
        const int fi  = tid + p * 256;   // float4 index 0..2047
        const int row = fi >> 8;
        const int col = (fi & 255) * 4;
        const float4 v = (col < 512)
          ? *reinterpret_cast<const float4*>(&A[(size_t)(d0 + row) * 512 + col])
          : *reinterpret_cast<const float4*>(&W[(size_t)(d0 + row) * 512 + (col - 512)]);
        *reinterpret_cast<float4*>(&stage[row * 1024 + col]) = v;
      }
      __syncthreads();
      #pragma unroll
      for (int r = 0; r < 8; ++r) {
        const int d = d0 + r;
        const uint32_t word = xmask[q][d >> 5];
        const bool on = ((word >> (d & 31)) & 1u) && (uint32_t)d != ii && (uint32_t)d != jj;
        if (on) {
          #pragma unroll
          for (int cc = 0; cc < 16; ++cc) {
            const float4 sv = *reinterpret_cast<const float4*>(
                &stage[r * 1024 + 4 * (t15 + 16 * cc)]);
            acc[cc][0] += sv.x; acc[cc][1] += sv.y;
            acc[cc][2] += sv.z; acc[cc][3] += sv.w;
          }
        }
      }
    }

    // ---- sampling ----
    uint32_t xw[8];
    #pragma unroll
    for (int cc = 0; cc < 8; ++cc) xw[cc] = xmask[q][2 * cc + h];

    const float* Ai = A + (size_t)ii * 512;
    const float* Aj = A + (size_t)jj * 512;
    const float* Wi = W + (size_t)ii * 512;
    const float* Wj = W + (size_t)jj * 512;

    float logits4[4];
    #pragma unroll
    for (int c = 0; c < 4; ++c) {
      const int ci = (c >> 1) & 1, cj = c & 1;
      // E1: A-part (cols 0..511), membership = x bits with i,j overridden
      float s1 = 0.f;
      #pragma unroll
      for (int cc = 0; cc < 8; ++cc) {
        const uint32_t wword = xw[cc];
        #pragma unroll
        for (int e4 = 0; e4 < 4; ++e4) {
          const int col  = 4 * t15 + 64 * cc + e4;
          const int bpos = (4 * t15 + e4) & 31;
          bool mem;
          if ((uint32_t)col == ii)      mem = (ci != 0);
          else if ((uint32_t)col == jj) mem = (cj != 0);
          else                          mem = ((wword >> bpos) & 1u) != 0;
          if (mem) {
            float v = acc[cc][e4];
            if (ci) v += Ai[col];
            if (cj) v += Aj[col];
            s1 += v;
          }
        }
      }
      // E2: W-part (cols 512..1023), membership = z bits
      float s2 = 0.f;
      #pragma unroll
      for (int cc = 8; cc < 16; ++cc) {
        const uint32_t zword = zw[cc - 8];
        #pragma unroll
        for (int e4 = 0; e4 < 4; ++e4) {
          const int k    = 4 * t15 + 64 * (cc - 8) + e4;
          const int bpos = (4 * t15 + e4) & 31;
          if ((zword >> bpos) & 1u) {
            float v = acc[cc][e4];
            if (ci) v += Wi[k];
            if (cj) v += Wj[k];
            s2 += v;
          }
        }
      }
      // canonical cross-lane tree (butterfly; all 16 lanes converge)
      #pragma unroll
      for (int msk = 1; msk < 16; msk <<= 1) {
        s1 += __shfl_xor(s1, msk, 64);
        s2 += __shfl_xor(s2, msk, 64);
      }
      logits4[c] = s1 + s2;
    }

    // gumbel + argmax (uniform across the 16 lanes of this chain)
    int best = 0;
    float bv = -3.0e38f;
    #pragma unroll
    for (int c = 0; c < 4; ++c) {
      const uint32_t m    = chain_g * 4u + (uint32_t)c;
      const uint32_t bits = rbits32(ks0, ks1, m, 32768u);
      float u = __uint_as_float(0x3f800000u | (bits >> 9)) - 1.0f;
      u = fmaxf(u + 1.17549435e-38f, 1.17549435e-38f);
      const float g = -logf(-logf(u));
      const float v = g + logits4[c];
      if (v > bv) { bv = v; best = c; }
    }

    // update x bits i,j (one lane per chain; wave-private, no barrier needed)
    if (t15 == 0) {
      const uint32_t iv = (uint32_t)(best >> 1), jv = (uint32_t)(best & 1);
      uint32_t wi = xmask[q][ii >> 5];
      wi = (wi & ~(1u << (ii & 31))) | (iv << (ii & 31));
      xmask[q][ii >> 5] = wi;
      uint32_t wj = xmask[q][jj >> 5];
      wj = (wj & ~(1u << (jj & 31))) | (jv << (jj & 31));
      xmask[q][jj >> 5] = wj;
    }
  }

  // ---- write output: out[chain_g*512 + col] in {0,1} f32 ----
  {
    const uint32_t word = xmask[q][t15];
    float* op = out + (size_t)chain_g * DDIM + 32 * t15;
    #pragma unroll
    for (int g4 = 0; g4 < 8; ++g4) {
      float4 o;
      o.x = (float)((word >> (4 * g4 + 0)) & 1u);
      o.y = (float)((word >> (4 * g4 + 1)) & 1u);
      o.z = (float)((word >> (4 * g4 + 2)) & 1u);
      o.w = (float)((word >> (4 * g4 + 3)) & 1u);
      *reinterpret_cast<float4*>(&op[4 * g4]) = o;
    }
  }
}

extern "C" void kernel_launch(void* const* d_in, const int* in_sizes, int n_in,
                              void* d_out, int out_size, void* d_ws, size_t ws_size,
                              hipStream_t stream) {
  const float* z = (const float*)d_in[0];   // (128, 512)
  const float* A = (const float*)d_in[1];   // (512, 512)
  const float* W = (const float*)d_in[2];   // (512, 512)
  float* out = (float*)d_out;               // (128, 128, 512)
  uint32_t* tbl = (uint32_t*)d_ws;          // 20 x {i, j, ks0, ks1}

  hipLaunchKernelGGL(gibbs_steps_kernel, dim3(MIX_TIME), dim3(64), 0, stream, tbl);
  hipLaunchKernelGGL(gibbs_main_kernel, dim3(NCHAIN / CHAINS_PER_BLOCK), dim3(256),
                     0, stream, A, W, z, tbl, out);
}

// Round 2
// 239.190 us; speedup vs baseline: 20.8722x; 20.8722x over previous
//
#include <hip/hip_runtime.h>
#include <stdint.h>

// ============================================================================
// Bit-exact JAX Gibbs sampler — R2: incremental sufficient statistics.
// R1 validated all PRNG semantics (partitionable threefry) with absmax 0.0.
// This round replaces the per-step full [A|W] staging (42 GB L2 traffic) with
// per-chain maintained T[e] = sum_{d in ones(x)} A[d,e] and precomputed
// c[b][d] = sum_k W[d,k] z[b,k].  One wave per chain, registers only.
// ============================================================================
#define JAX_PARTITIONABLE 1

#define MIX_TIME 20
#define NCHAIN   16384   // S*B = 128*128
#define DDIM     512

struct U2 { uint32_t a, b; };

__device__ __forceinline__ uint32_t rotl32(uint32_t v, int r) {
  return (v << r) | (v >> (32 - r));
}

// Threefry-2x32, 20 rounds (JAX prng.py / Random123).
__device__ __forceinline__ U2 tf2x32(uint32_t k0, uint32_t k1, uint32_t x0, uint32_t x1) {
  const uint32_t ks2 = k0 ^ k1 ^ 0x1BD11BDAu;
  x0 += k0; x1 += k1;
  x0 += x1; x1 = rotl32(x1, 13); x1 ^= x0;
  x0 += x1; x1 = rotl32(x1, 15); x1 ^= x0;
  x0 += x1; x1 = rotl32(x1, 26); x1 ^= x0;
  x0 += x1; x1 = rotl32(x1,  6); x1 ^= x0;
  x0 += k1; x1 += ks2 + 1u;
  x0 += x1; x1 = rotl32(x1, 17); x1 ^= x0;
  x0 += x1; x1 = rotl32(x1, 29); x1 ^= x0;
  x0 += x1; x1 = rotl32(x1, 16); x1 ^= x0;
  x0 += x1; x1 = rotl32(x1, 24); x1 ^= x0;
  x0 += ks2; x1 += k0 + 2u;
  x0 += x1; x1 = rotl32(x1, 13); x1 ^= x0;
  x0 += x1; x1 = rotl32(x1, 15); x1 ^= x0;
  x0 += x1; x1 = rotl32(x1, 26); x1 ^= x0;
  x0 += x1; x1 = rotl32(x1,  6); x1 ^= x0;
  x0 += k0; x1 += k1 + 3u;
  x0 += x1; x1 = rotl32(x1, 17); x1 ^= x0;
  x0 += x1; x1 = rotl32(x1, 29); x1 ^= x0;
  x0 += x1; x1 = rotl32(x1, 16); x1 ^= x0;
  x0 += x1; x1 = rotl32(x1, 24); x1 ^= x0;
  x0 += k1; x1 += ks2 + 4u;
  x0 += x1; x1 = rotl32(x1, 13); x1 ^= x0;
  x0 += x1; x1 = rotl32(x1, 15); x1 ^= x0;
  x0 += x1; x1 = rotl32(x1, 26); x1 ^= x0;
  x0 += x1; x1 = rotl32(x1,  6); x1 ^= x0;
  x0 += ks2; x1 += k0 + 5u;
  return {x0, x1};
}

__device__ __forceinline__ uint32_t rbits32(uint32_t k0, uint32_t k1,
                                            uint32_t m, uint32_t half) {
#if JAX_PARTITIONABLE
  U2 r = tf2x32(k0, k1, 0u, m);
  return r.a ^ r.b;
#else
  if (m < half) { return tf2x32(k0, k1, m, half + m).a; }
  else          { return tf2x32(k0, k1, m - half, m).b; }
#endif
}

__device__ __forceinline__ U2 split_key(uint32_t k0, uint32_t k1,
                                        uint32_t idx, uint32_t num) {
#if JAX_PARTITIONABLE
  return tf2x32(k0, k1, 0u, idx);
#else
  const uint32_t m0 = 2u * idx, m1 = 2u * idx + 1u;
  const uint32_t w0 = (m0 < num) ? tf2x32(k0, k1, m0, num + m0).a
                                 : tf2x32(k0, k1, m0 - num, m0).b;
  const uint32_t w1 = (m1 < num) ? tf2x32(k0, k1, m1, num + m1).a
                                 : tf2x32(k0, k1, m1 - num, m1).b;
  return {w0, w1};
#endif
}

// select A[p] (p runtime-uniform) without scratch: constant-index ternary tree
#define SEL8(A, p) ((p) < 4 ? ((p) < 2 ? ((p) == 0 ? (A)[0] : (A)[1])   \
                                       : ((p) == 2 ? (A)[2] : (A)[3]))  \
                            : ((p) < 6 ? ((p) == 4 ? (A)[4] : (A)[5])   \
                                       : ((p) == 6 ? (A)[6] : (A)[7])))

// ============================================================================
// Kernel 1 (unchanged, validated): per-step {i, j, ks0, ks1}.
// ============================================================================
__global__ __launch_bounds__(64)
void gibbs_steps_kernel(uint32_t* __restrict__ tbl) {
  const uint32_t t    = blockIdx.x;
  const uint32_t lane = threadIdx.x;

  const U2 K   = split_key(0u, 1u, t, (uint32_t)MIX_TIME);
  const U2 ki  = split_key(K.a, K.b, 0u, 2u);
  const U2 ks  = split_key(K.a, K.b, 1u, 2u);
  const U2 sub = split_key(ki.a, ki.b, 1u, 2u);

  uint32_t k1 = 0xFFFFFFFFu, m1 = 0xFFFFFFFFu;
  uint32_t k2 = 0xFFFFFFFFu, m2 = 0xFFFFFFFFu;
  #pragma unroll
  for (int p = 0; p < 8; ++p) {
    const uint32_t m   = lane + 64u * (uint32_t)p;
    const uint32_t key = rbits32(sub.a, sub.b, m, 256u);
    const bool lt1 = (key < k1) || (key == k1 && m < m1);
    const bool lt2 = (key < k2) || (key == k2 && m < m2);
    if (lt1)      { k2 = k1; m2 = m1; k1 = key; m1 = m; }
    else if (lt2) { k2 = key; m2 = m; }
  }
  #pragma unroll
  for (int msk = 1; msk < 64; msk <<= 1) {
    const uint32_t ok1 = __shfl_xor((int)k1, msk, 64);
    const uint32_t om1 = __shfl_xor((int)m1, msk, 64);
    const uint32_t ok2 = __shfl_xor((int)k2, msk, 64);
    const uint32_t om2 = __shfl_xor((int)m2, msk, 64);
    const bool oless = (ok1 < k1) || (ok1 == k1 && om1 < m1);
    if (oless) {
      const bool l2 = (k1 < ok2) || (k1 == ok2 && m1 < om2);
      const uint32_t nk2 = l2 ? k1 : ok2, nm2 = l2 ? m1 : om2;
      k1 = ok1; m1 = om1; k2 = nk2; m2 = nm2;
    } else {
      const bool l2 = (ok1 < k2) || (ok1 == k2 && om1 < m2);
      if (l2) { k2 = ok1; m2 = om1; }
    }
  }
  if (lane == 0) {
    tbl[4u * t + 0u] = m1;
    tbl[4u * t + 1u] = m2;
    tbl[4u * t + 2u] = ks.a;
    tbl[4u * t + 3u] = ks.b;
  }
}

// ============================================================================
// Kernel 2: T0[e] = sum_{d=0..63} A[d,e]  (identical for all chains)
// ============================================================================
__global__ __launch_bounds__(256)
void t0_kernel(const float* __restrict__ A, float* __restrict__ T0) {
  const int e = blockIdx.x * 256 + threadIdx.x;
  float s = 0.f;
  #pragma unroll 1
  for (int d = 0; d < 64; ++d) s += A[(size_t)d * DDIM + e];
  T0[e] = s;
}

// ============================================================================
// Kernel 3: C[b][d] = sum_k W[d,k] * z[b,k]
// ============================================================================
__global__ __launch_bounds__(256)
void c_kernel(const float* __restrict__ W, const float* __restrict__ z,
              float* __restrict__ C) {
  const int b   = blockIdx.x;
  const int tid = threadIdx.x;
  __shared__ float zs[DDIM];
  zs[tid]       = z[(size_t)b * DDIM + tid];
  zs[tid + 256] = z[(size_t)b * DDIM + tid + 256];
  __syncthreads();
  #pragma unroll 1
  for (int d = tid; d < DDIM; d += 256) {
    const float* Wr = W + (size_t)d * DDIM;
    float s = 0.f;
    #pragma unroll 4
    for (int k = 0; k < DDIM; ++k) s += Wr[k] * zs[k];
    C[(size_t)b * DDIM + d] = s;
  }
}

// ============================================================================
// Kernel 4: the sampler.  One wave per chain; 4 waves / 256-thread block.
// Lane L owns elements e = L + 64*p, p = 0..7, of all 512-vectors.
// State: T[8] (running column sums), cb[8] (W·z for this batch), m8 (x bits).
// ============================================================================
__global__ __launch_bounds__(256)
void gibbs_fast_kernel(const float* __restrict__ A,
                       const uint32_t* __restrict__ tbl,
                       const float* __restrict__ T0,
                       const float* __restrict__ C,
                       float* __restrict__ out) {
  const int tid = threadIdx.x;
  const int L   = tid & 63;
  const int wv  = tid >> 6;
  const uint32_t chain = (uint32_t)blockIdx.x * 4u + (uint32_t)wv;  // s*128 + b
  const uint32_t b     = chain & 127u;

  float T[8], cb[8];
  #pragma unroll
  for (int p = 0; p < 8; ++p) {
    T[p]  = T0[L + 64 * p];
    cb[p] = C[(size_t)b * DDIM + L + 64 * p];
  }
  uint32_t m8 = 1u;   // x[e]=1 iff e<64  <=>  p==0 slot set on every lane

  #pragma unroll 1
  for (int t = 0; t < MIX_TIME; ++t) {
    const uint32_t ii  = tbl[4 * t + 0];
    const uint32_t jj  = tbl[4 * t + 1];
    const uint32_t ks0 = tbl[4 * t + 2];
    const uint32_t ks1 = tbl[4 * t + 3];
    const int lane_i = (int)(ii & 63u), pi = (int)(ii >> 6);
    const int lane_j = (int)(jj & 63u), pj = (int)(jj >> 6);

    float Ai[8], Aj[8];
    #pragma unroll
    for (int p = 0; p < 8; ++p) {
      Ai[p] = A[(size_t)ii * DDIM + L + 64 * p];
      Aj[p] = A[(size_t)jj * DDIM + L + 64 * p];
    }

    const uint32_t m8i = (uint32_t)__shfl((int)m8, lane_i, 64);
    const uint32_t m8j = (uint32_t)__shfl((int)m8, lane_j, 64);
    const int xi = (int)((m8i >> pi) & 1u);
    const int xj = (int)((m8j >> pj) & 1u);

    uint32_t mR = m8;
    if (L == lane_i) mR &= ~(1u << pi);
    if (L == lane_j) mR &= ~(1u << pj);

    // masked partial sums over R (this lane's 8 slots)
    float sT = 0.f, si = 0.f, sj = 0.f, sz = 0.f;
    #pragma unroll
    for (int p = 0; p < 8; ++p) {
      if ((mR >> p) & 1u) { sT += T[p]; si += Ai[p]; sj += Aj[p]; sz += cb[p]; }
    }
    #pragma unroll
    for (int msk = 1; msk < 64; msk <<= 1) {
      sT += __shfl_xor(sT, msk, 64);
      si += __shfl_xor(si, msk, 64);
      sj += __shfl_xor(sj, msk, 64);
      sz += __shfl_xor(sz, msk, 64);
    }

    // scalar extracts (all lanes compute SEL8, shfl from the owning lane)
    const float Ti  = __shfl(SEL8(T,  pi), lane_i, 64);
    const float Tj  = __shfl(SEL8(T,  pj), lane_j, 64);
    const float Aii = __shfl(SEL8(Ai, pi), lane_i, 64);   // A[i,i]
    const float Aij = __shfl(SEL8(Ai, pj), lane_j, 64);   // A[i,j]
    const float Aji = __shfl(SEL8(Aj, pi), lane_i, 64);   // A[j,i]
    const float Ajj = __shfl(SEL8(Aj, pj), lane_j, 64);   // A[j,j]
    const float ci  = __shfl(SEL8(cb, pi), lane_i, 64);   // (Wz)_i
    const float cj  = __shfl(SEL8(cb, pj), lane_j, 64);   // (Wz)_j

    const float fxi = (float)xi, fxj = (float)xj;
    const float QR   = sT - fxi * si - fxj * sj;   // exact: fxi in {0,1}
    const float coli = Ti - fxi * Aii - fxj * Aji;
    const float colj = Tj - fxi * Aij - fxj * Ajj;
    const float base = QR + sz;
    const float gi   = si + coli + Aii + ci;   // coefficient of a
    const float gj   = sj + colj + Ajj + cj;   // coefficient of b
    const float gij  = Aij + Aji;              // coefficient of a*b

    // gumbel + logits; lane group c4 = L&3 handles combo c4 (groups identical)
    const int c4 = L & 3;
    const uint32_t m    = chain * 4u + (uint32_t)c4;
    const uint32_t bits = rbits32(ks0, ks1, m, 0u);
    float u = __uint_as_float(0x3f800000u | (bits >> 9)) - 1.0f;
    u = fmaxf(u + 1.17549435e-38f, 1.17549435e-38f);
    const float g  = -logf(-logf(u));
    const float fa = (float)((c4 >> 1) & 1), fb = (float)(c4 & 1);
    const float v  = g + (base + fa * gi + fb * gj + (fa * fb) * gij);

    // first-max argmax over the 4 combos (butterfly within lane groups of 4)
    int   bestc = c4;
    float bv    = v;
    #pragma unroll
    for (int msk = 1; msk < 4; msk <<= 1) {
      const float ov = __shfl_xor(bv, msk, 64);
      const int   oc = __shfl_xor(bestc, msk, 64);
      if (ov > bv || (ov == bv && oc < bestc)) { bv = ov; bestc = oc; }
    }

    const int a_new = (bestc >> 1) & 1, b_new = bestc & 1;
    const int di = a_new - xi, dj = b_new - xj;
    if (di != 0) {
      const float s = (float)di;   // ±1: exact add/sub of the row
      #pragma unroll
      for (int p = 0; p < 8; ++p) T[p] += s * Ai[p];
    }
    if (dj != 0) {
      const float s = (float)dj;
      #pragma unroll
      for (int p = 0; p < 8; ++p) T[p] += s * Aj[p];
    }
    if (L == lane_i) m8 = (m8 & ~(1u << pi)) | ((uint32_t)a_new << pi);
    if (L == lane_j) m8 = (m8 & ~(1u << pj)) | ((uint32_t)b_new << pj);
  }

  // write output {0,1} f32
  #pragma unroll
  for (int p = 0; p < 8; ++p)
    out[(size_t)chain * DDIM + L + 64 * p] = (float)((m8 >> p) & 1u);
}

extern "C" void kernel_launch(void* const* d_in, const int* in_sizes, int n_in,
                              void* d_out, int out_size, void* d_ws, size_t ws_size,
                              hipStream_t stream) {
  const float* z = (const float*)d_in[0];   // (128, 512)
  const float* A = (const float*)d_in[1];   // (512, 512)
  const float* W = (const float*)d_in[2];   // (512, 512)
  float* out = (float*)d_out;               // (128, 128, 512)

  // ws layout: tbl[128 u32] | T0[512 f32] | C[128*512 f32]  (~265 KB)
  uint32_t* tbl = (uint32_t*)d_ws;
  float*    T0  = (float*)d_ws + 128;
  float*    C   = (float*)d_ws + 128 + DDIM;

  hipLaunchKernelGGL(gibbs_steps_kernel, dim3(MIX_TIME), dim3(64), 0, stream, tbl);
  hipLaunchKernelGGL(t0_kernel, dim3(2), dim3(256), 0, stream, A, T0);
  hipLaunchKernelGGL(c_kernel, dim3(128), dim3(256), 0, stream, W, z, C);
  hipLaunchKernelGGL(gibbs_fast_kernel, dim3(NCHAIN / 4), dim3(256), 0, stream,
                     A, tbl, T0, C, out);
}

// Round 3
// 145.654 us; speedup vs baseline: 34.2759x; 1.6422x over previous
//
#include <hip/hip_runtime.h>
#include <stdint.h>

// ============================================================================
// Bit-exact JAX Gibbs sampler — R3: amortized gumbels + incremental St/Sz +
// precomputed per-step scalars + float4 lane layout.
// R1/R2 validated PRNG semantics (partitionable threefry) with absmax 0.0.
// ============================================================================
#define JAX_PARTITIONABLE 1

#define MIX_TIME 20
#define NCHAIN   16384   // S*B = 128*128
#define DDIM     512

struct U2 { uint32_t a, b; };

__device__ __forceinline__ uint32_t rotl32(uint32_t v, int r) {
  return (v << r) | (v >> (32 - r));
}

// Threefry-2x32, 20 rounds (JAX prng.py / Random123).
__device__ __forceinline__ U2 tf2x32(uint32_t k0, uint32_t k1, uint32_t x0, uint32_t x1) {
  const uint32_t ks2 = k0 ^ k1 ^ 0x1BD11BDAu;
  x0 += k0; x1 += k1;
  x0 += x1; x1 = rotl32(x1, 13); x1 ^= x0;
  x0 += x1; x1 = rotl32(x1, 15); x1 ^= x0;
  x0 += x1; x1 = rotl32(x1, 26); x1 ^= x0;
  x0 += x1; x1 = rotl32(x1,  6); x1 ^= x0;
  x0 += k1; x1 += ks2 + 1u;
  x0 += x1; x1 = rotl32(x1, 17); x1 ^= x0;
  x0 += x1; x1 = rotl32(x1, 29); x1 ^= x0;
  x0 += x1; x1 = rotl32(x1, 16); x1 ^= x0;
  x0 += x1; x1 = rotl32(x1, 24); x1 ^= x0;
  x0 += ks2; x1 += k0 + 2u;
  x0 += x1; x1 = rotl32(x1, 13); x1 ^= x0;
  x0 += x1; x1 = rotl32(x1, 15); x1 ^= x0;
  x0 += x1; x1 = rotl32(x1, 26); x1 ^= x0;
  x0 += x1; x1 = rotl32(x1,  6); x1 ^= x0;
  x0 += k0; x1 += k1 + 3u;
  x0 += x1; x1 = rotl32(x1, 17); x1 ^= x0;
  x0 += x1; x1 = rotl32(x1, 29); x1 ^= x0;
  x0 += x1; x1 = rotl32(x1, 16); x1 ^= x0;
  x0 += x1; x1 = rotl32(x1, 24); x1 ^= x0;
  x0 += k1; x1 += ks2 + 4u;
  x0 += x1; x1 = rotl32(x1, 13); x1 ^= x0;
  x0 += x1; x1 = rotl32(x1, 15); x1 ^= x0;
  x0 += x1; x1 = rotl32(x1, 26); x1 ^= x0;
  x0 += x1; x1 = rotl32(x1,  6); x1 ^= x0;
  x0 += ks2; x1 += k0 + 5u;
  return {x0, x1};
}

__device__ __forceinline__ uint32_t rbits32(uint32_t k0, uint32_t k1, uint32_t m) {
#if JAX_PARTITIONABLE
  U2 r = tf2x32(k0, k1, 0u, m);
  return r.a ^ r.b;
#else
  return 0u;
#endif
}

__device__ __forceinline__ U2 split_key(uint32_t k0, uint32_t k1,
                                        uint32_t idx, uint32_t num) {
#if JAX_PARTITIONABLE
  (void)num;
  return tf2x32(k0, k1, 0u, idx);
#else
  return {0u, 0u};
#endif
}

__device__ __forceinline__ uint32_t rfl_u32(uint32_t v) {
  return (uint32_t)__builtin_amdgcn_readfirstlane((int)v);
}
__device__ __forceinline__ float rfl_f32(float v) {
  return __uint_as_float(rfl_u32(__float_as_uint(v)));
}

// select A[p] (p wave-uniform) without scratch: constant-index select tree
#define SEL8(A, p) ((p) < 4 ? ((p) < 2 ? ((p) == 0 ? (A)[0] : (A)[1])   \
                                       : ((p) == 2 ? (A)[2] : (A)[3]))  \
                            : ((p) < 6 ? ((p) == 4 ? (A)[4] : (A)[5])   \
                                       : ((p) == 6 ? (A)[6] : (A)[7])))

// gumbel from raw bits — expression identical to R1/R2 (bit-exact g)
__device__ __forceinline__ float gumbel_from(uint32_t bits) {
  float u = __uint_as_float(0x3f800000u | (bits >> 9)) - 1.0f;
  u = fmaxf(u + 1.17549435e-38f, 1.17549435e-38f);
  return -logf(-logf(u));
}

// ============================================================================
// Kernel A (fused): blocks 0..19 steps-table, 20..21 T0, 22..149 C = W z^T
// ============================================================================
__global__ __launch_bounds__(256)
void pre_kernel(const float* __restrict__ A, const float* __restrict__ W,
                const float* __restrict__ z, uint32_t* __restrict__ tbl,
                float* __restrict__ T0, float* __restrict__ C) {
  const int bid = blockIdx.x, tid = threadIdx.x;
  __shared__ float4 zs4[128];

  if (bid < MIX_TIME) {
    if (tid < 64) {
      const uint32_t t    = (uint32_t)bid;
      const uint32_t lane = (uint32_t)tid;
      const U2 K   = split_key(0u, 1u, t, (uint32_t)MIX_TIME);
      const U2 ki  = split_key(K.a, K.b, 0u, 2u);
      const U2 ks  = split_key(K.a, K.b, 1u, 2u);
      const U2 sub = split_key(ki.a, ki.b, 1u, 2u);

      uint32_t k1 = 0xFFFFFFFFu, m1 = 0xFFFFFFFFu;
      uint32_t k2 = 0xFFFFFFFFu, m2 = 0xFFFFFFFFu;
      #pragma unroll
      for (int p = 0; p < 8; ++p) {
        const uint32_t m   = lane + 64u * (uint32_t)p;
        const uint32_t key = rbits32(sub.a, sub.b, m);
        const bool lt1 = (key < k1) || (key == k1 && m < m1);
        const bool lt2 = (key < k2) || (key == k2 && m < m2);
        if (lt1)      { k2 = k1; m2 = m1; k1 = key; m1 = m; }
        else if (lt2) { k2 = key; m2 = m; }
      }
      #pragma unroll
      for (int msk = 1; msk < 64; msk <<= 1) {
        const uint32_t ok1 = __shfl_xor((int)k1, msk, 64);
        const uint32_t om1 = __shfl_xor((int)m1, msk, 64);
        const uint32_t ok2 = __shfl_xor((int)k2, msk, 64);
        const uint32_t om2 = __shfl_xor((int)m2, msk, 64);
        const bool oless = (ok1 < k1) || (ok1 == k1 && om1 < m1);
        if (oless) {
          const bool l2 = (k1 < ok2) || (k1 == ok2 && m1 < om2);
          const uint32_t nk2 = l2 ? k1 : ok2, nm2 = l2 ? m1 : om2;
          k1 = ok1; m1 = om1; k2 = nk2; m2 = nm2;
        } else {
          const bool l2 = (ok1 < k2) || (ok1 == k2 && om1 < m2);
          if (l2) { k2 = ok1; m2 = om1; }
        }
      }
      if (lane == 0) {
        tbl[4u * t + 0u] = m1;
        tbl[4u * t + 1u] = m2;
        tbl[4u * t + 2u] = ks.a;
        tbl[4u * t + 3u] = ks.b;
      }
    }
    return;
  }

  if (bid < MIX_TIME + 2) {
    const int e = (bid - MIX_TIME) * 256 + tid;
    float s = 0.f;
    #pragma unroll 1
    for (int d = 0; d < 64; ++d) s += A[(size_t)d * DDIM + e];
    T0[e] = s;
    return;
  }

  const int b = bid - (MIX_TIME + 2);
  if (tid < 128) zs4[tid] = reinterpret_cast<const float4*>(z + (size_t)b * DDIM)[tid];
  __syncthreads();
  #pragma unroll
  for (int rr = 0; rr < 2; ++rr) {
    const int d = tid + rr * 256;
    const float4* Wr = reinterpret_cast<const float4*>(W + (size_t)d * DDIM);
    float s = 0.f;
    #pragma unroll 4
    for (int k = 0; k < 128; ++k) {
      const float4 w = Wr[k], zz = zs4[k];
      s = fmaf(w.x, zz.x, s); s = fmaf(w.y, zz.y, s);
      s = fmaf(w.z, zz.z, s); s = fmaf(w.w, zz.w, s);
    }
    C[(size_t)b * DDIM + d] = s;
  }
}

// ============================================================================
// Kernel B: per-step scalars sc[t] = {i, j, Aii, Aij, Aji, Ajj, 0, 0}
//           and ct[t][b] = {C[b][i_t], C[b][j_t]}.  One block.
// ============================================================================
__global__ __launch_bounds__(256)
void scal_kernel(const float* __restrict__ A, const uint32_t* __restrict__ tbl,
                 const float* __restrict__ C, uint32_t* __restrict__ sc,
                 float* __restrict__ ct) {
  const int tid = threadIdx.x;
  if (tid < MIX_TIME) {
    const uint32_t i = tbl[4 * tid], j = tbl[4 * tid + 1];
    uint32_t* s = sc + 8 * tid;
    s[0] = i; s[1] = j;
    s[2] = __float_as_uint(A[(size_t)i * DDIM + i]);
    s[3] = __float_as_uint(A[(size_t)i * DDIM + j]);
    s[4] = __float_as_uint(A[(size_t)j * DDIM + i]);
    s[5] = __float_as_uint(A[(size_t)j * DDIM + j]);
    s[6] = 0u; s[7] = 0u;
  }
  #pragma unroll 1
  for (int p = tid; p < MIX_TIME * 128; p += 256) {
    const int t = p >> 7, b = p & 127;
    const uint32_t i = tbl[4 * t], j = tbl[4 * t + 1];
    ct[2 * p]     = C[(size_t)b * DDIM + i];
    ct[2 * p + 1] = C[(size_t)b * DDIM + j];
  }
}

// ============================================================================
// Kernel C: sampler.  One wave per chain; lane L owns elements {4L..4L+3} and
// {256+4L..256+4L+3} (slots 0..7).  T, cb, mask in registers; gumbels batched.
// ============================================================================
__global__ __launch_bounds__(256)
void gibbs_fast2_kernel(const float* __restrict__ A,
                        const uint32_t* __restrict__ tbl,
                        const uint32_t* __restrict__ sc,
                        const float* __restrict__ ct,
                        const float* __restrict__ T0,
                        const float* __restrict__ C,
                        float* __restrict__ out) {
  const int tid = threadIdx.x;
  const int L   = tid & 63;
  const uint32_t chain = (uint32_t)blockIdx.x * 4u + (uint32_t)(tid >> 6);
  const uint32_t b     = chain & 127u;

  float T[8], cb[8];
  {
    const float4* tv = reinterpret_cast<const float4*>(T0);
    const float4 a0 = tv[L], a1 = tv[64 + L];
    T[0]=a0.x; T[1]=a0.y; T[2]=a0.z; T[3]=a0.w;
    T[4]=a1.x; T[5]=a1.y; T[6]=a1.z; T[7]=a1.w;
    const float4* cv = reinterpret_cast<const float4*>(C + (size_t)b * DDIM);
    const float4 c0 = cv[L], c1 = cv[64 + L];
    cb[0]=c0.x; cb[1]=c0.y; cb[2]=c0.z; cb[3]=c0.w;
    cb[4]=c1.x; cb[5]=c1.y; cb[6]=c1.z; cb[7]=c1.w;
  }
  uint32_t m8 = (L < 16) ? 0xFu : 0u;   // x0: e<64 set

  // batched gumbels: g0 holds (t=L>>2, c=L&3); g1 holds (t=16+((L>>2)&3), c=L&3)
  float g0, g1;
  {
    const uint32_t m = chain * 4u + (uint32_t)(L & 3);
    const int ta = L >> 2;
    g0 = gumbel_from(rbits32(tbl[4 * ta + 2], tbl[4 * ta + 3], m));
    const int tb2 = 16 + ((L >> 2) & 3);
    g1 = gumbel_from(rbits32(tbl[4 * tb2 + 2], tbl[4 * tb2 + 3], m));
  }

  // St = sum_{ones} T, Sz = sum_{ones} cb (maintained incrementally)
  float St = 0.f, Sz = 0.f;
  #pragma unroll
  for (int p = 0; p < 8; ++p) {
    const float mf = (float)((m8 >> p) & 1u);
    St = fmaf(mf, T[p], St);
    Sz = fmaf(mf, cb[p], Sz);
  }
  #pragma unroll
  for (int msk = 1; msk < 64; msk <<= 1) {
    St += __shfl_xor(St, msk, 64);
    Sz += __shfl_xor(Sz, msk, 64);
  }

  #pragma unroll 1
  for (int t = 0; t < MIX_TIME; ++t) {
    const uint32_t* scp = sc + 8 * t;
    const uint4 u0 = *reinterpret_cast<const uint4*>(scp);
    const uint2 u1 = *reinterpret_cast<const uint2*>(scp + 4);
    const uint32_t ii = rfl_u32(u0.x), jj = rfl_u32(u0.y);
    const float Aii = rfl_f32(__uint_as_float(u0.z));
    const float Aij = rfl_f32(__uint_as_float(u0.w));
    const float Aji = rfl_f32(__uint_as_float(u1.x));
    const float Ajj = rfl_f32(__uint_as_float(u1.y));
    const float2 cij = *reinterpret_cast<const float2*>(ct + 2 * (t * 128 + (int)b));
    const float ci = rfl_f32(cij.x), cj = rfl_f32(cij.y);

    const int lane_i = (int)((ii >> 2) & 63u), slot_i = (int)((ii & 3u) | ((ii >> 6) & 4u));
    const int lane_j = (int)((jj >> 2) & 63u), slot_j = (int)((jj & 3u) | ((jj >> 6) & 4u));

    float Ai[8], Aj[8];
    {
      const float4* av = reinterpret_cast<const float4*>(A + (size_t)ii * DDIM);
      const float4 a0 = av[L], a1 = av[64 + L];
      Ai[0]=a0.x; Ai[1]=a0.y; Ai[2]=a0.z; Ai[3]=a0.w;
      Ai[4]=a1.x; Ai[5]=a1.y; Ai[6]=a1.z; Ai[7]=a1.w;
      const float4* bv = reinterpret_cast<const float4*>(A + (size_t)jj * DDIM);
      const float4 b0 = bv[L], b1 = bv[64 + L];
      Aj[0]=b0.x; Aj[1]=b0.y; Aj[2]=b0.z; Aj[3]=b0.w;
      Aj[4]=b1.x; Aj[5]=b1.y; Aj[6]=b1.z; Aj[7]=b1.w;
    }

    const uint32_t m8i = (uint32_t)__shfl((int)m8, lane_i, 64);
    const uint32_t m8j = (uint32_t)__shfl((int)m8, lane_j, 64);
    const int xi = (int)((m8i >> slot_i) & 1u);
    const int xj = (int)((m8j >> slot_j) & 1u);

    uint32_t mR = m8;
    if (L == lane_i) mR &= ~(1u << slot_i);
    if (L == lane_j) mR &= ~(1u << slot_j);

    float si = 0.f, sj = 0.f;
    #pragma unroll
    for (int p = 0; p < 8; ++p) {
      const float mf = (float)((mR >> p) & 1u);
      si = fmaf(mf, Ai[p], si);
      sj = fmaf(mf, Aj[p], sj);
    }
    #pragma unroll
    for (int msk = 1; msk < 64; msk <<= 1) {
      si += __shfl_xor(si, msk, 64);
      sj += __shfl_xor(sj, msk, 64);
    }

    const float Ti = __shfl(SEL8(T, slot_i), lane_i, 64);
    const float Tj = __shfl(SEL8(T, slot_j), lane_j, 64);

    const float fxi = (float)xi, fxj = (float)xj;
    const float sTR  = St - fxi * Ti - fxj * Tj;
    const float szR  = Sz - fxi * ci - fxj * cj;
    const float QR   = sTR - fxi * si - fxj * sj;
    const float coli = Ti - fxi * Aii - fxj * Aji;
    const float colj = Tj - fxi * Aij - fxj * Ajj;
    const float base = QR + szR;
    const float gi   = si + coli + Aii + ci;
    const float gj   = sj + colj + Ajj + cj;
    const float gij  = Aij + Aji;

    const int c4 = L & 3;
    const int srcl = 4 * ((t < 16) ? t : (t - 16)) + c4;
    const float g  = __shfl((t < 16) ? g0 : g1, srcl, 64);
    const float fa = (float)((c4 >> 1) & 1), fb = (float)(c4 & 1);
    const float v  = g + (base + fa * gi + fb * gj + (fa * fb) * gij);

    int   bestc = c4;
    float bv    = v;
    #pragma unroll
    for (int msk = 1; msk < 4; msk <<= 1) {
      const float ov = __shfl_xor(bv, msk, 64);
      const int   oc = __shfl_xor(bestc, msk, 64);
      if (ov > bv || (ov == bv && oc < bestc)) { bv = ov; bestc = oc; }
    }

    const int a_new = (bestc >> 1) & 1, b_new = bestc & 1;
    const int di = a_new - xi, dj = b_new - xj;
    if (di != 0) {
      const float s = (float)di;
      #pragma unroll
      for (int p = 0; p < 8; ++p) T[p] = fmaf(s, Ai[p], T[p]);
    }
    if (dj != 0) {
      const float s = (float)dj;
      #pragma unroll
      for (int p = 0; p < 8; ++p) T[p] = fmaf(s, Aj[p], T[p]);
    }
    const float fdi = (float)di, fdj = (float)dj;
    const float fan = (float)a_new, fbn = (float)b_new;
    St = St + fdi * Ti + fdj * Tj
            + fdi * (si + fan * Aii + fbn * Aij)
            + fdj * (sj + fan * Aji + fbn * Ajj);
    Sz = Sz + fdi * ci + fdj * cj;
    if (L == lane_i) m8 = (m8 & ~(1u << slot_i)) | ((uint32_t)a_new << slot_i);
    if (L == lane_j) m8 = (m8 & ~(1u << slot_j)) | ((uint32_t)b_new << slot_j);
  }

  // output {0,1} f32, two dwordx4 stores per lane
  float4 o0, o1;
  o0.x = (float)( m8        & 1u);
  o0.y = (float)((m8 >> 1)  & 1u);
  o0.z = (float)((m8 >> 2)  & 1u);
  o0.w = (float)((m8 >> 3)  & 1u);
  o1.x = (float)((m8 >> 4)  & 1u);
  o1.y = (float)((m8 >> 5)  & 1u);
  o1.z = (float)((m8 >> 6)  & 1u);
  o1.w = (float)((m8 >> 7)  & 1u);
  float4* ov = reinterpret_cast<float4*>(out + (size_t)chain * DDIM);
  ov[L]      = o0;
  ov[64 + L] = o1;
}

extern "C" void kernel_launch(void* const* d_in, const int* in_sizes, int n_in,
                              void* d_out, int out_size, void* d_ws, size_t ws_size,
                              hipStream_t stream) {
  const float* z = (const float*)d_in[0];   // (128, 512)
  const float* A = (const float*)d_in[1];   // (512, 512)
  const float* W = (const float*)d_in[2];   // (512, 512)
  float* out = (float*)d_out;               // (128, 128, 512)

  // ws layout (u32 units): tbl[0,80) pad to 128 | T0 512 f32 | C 65536 f32 |
  //                        sc 160 u32 | ct 5120 f32   (~286 KB)
  uint32_t* tbl = (uint32_t*)d_ws;
  float*    T0  = (float*)d_ws + 128;
  float*    C   = T0 + DDIM;
  uint32_t* sc  = (uint32_t*)(C + 128 * DDIM);
  float*    ct  = (float*)(sc + 8 * MIX_TIME);

  hipLaunchKernelGGL(pre_kernel, dim3(MIX_TIME + 2 + 128), dim3(256), 0, stream,
                     A, W, z, tbl, T0, C);
  hipLaunchKernelGGL(scal_kernel, dim3(1), dim3(256), 0, stream, A, tbl, C, sc, ct);
  hipLaunchKernelGGL(gibbs_fast2_kernel, dim3(NCHAIN / 4), dim3(256), 0, stream,
                     A, tbl, sc, ct, T0, C, out);
}

// Round 4
// 97.149 us; speedup vs baseline: 51.3893x; 1.4993x over previous
//
#include <hip/hip_runtime.h>
#include <stdint.h>

// ============================================================================
// Bit-exact JAX Gibbs sampler — R4: O(1)-per-step via 40x40 coupling matrix.
// All chains share coords (i_t, j_t). Lane t' of each 32-lane half maintains
// the CURRENT values of T[i_t'], T[j_t'], U[i_t'], U[j_t'] (col/row sums of A
// over the ones-set), updated lane-parallel from G = A[coords, coords] in LDS.
// 2 chains per wave. No per-step row loads, no butterflies, no SEL trees.
// ============================================================================
#define MIX_TIME 20
#define NCHAIN   16384   // S*B = 128*128
#define DDIM     512

// ws layout in 4-byte units
#define WS_TBL 0
#define WS_T0  128
#define WS_U0  640
#define WS_C   1152
#define WS_SC  66688
#define WS_CT  66848
#define WS_G   71968
#define WS_GT  73568
#define WS_SZ0 75168
#define WS_ST0 75296

struct U2 { uint32_t a, b; };

__device__ __forceinline__ uint32_t rotl32(uint32_t v, int r) {
  return (v << r) | (v >> (32 - r));
}

// Threefry-2x32, 20 rounds (JAX prng.py / Random123).
__device__ __forceinline__ U2 tf2x32(uint32_t k0, uint32_t k1, uint32_t x0, uint32_t x1) {
  const uint32_t ks2 = k0 ^ k1 ^ 0x1BD11BDAu;
  x0 += k0; x1 += k1;
  x0 += x1; x1 = rotl32(x1, 13); x1 ^= x0;
  x0 += x1; x1 = rotl32(x1, 15); x1 ^= x0;
  x0 += x1; x1 = rotl32(x1, 26); x1 ^= x0;
  x0 += x1; x1 = rotl32(x1,  6); x1 ^= x0;
  x0 += k1; x1 += ks2 + 1u;
  x0 += x1; x1 = rotl32(x1, 17); x1 ^= x0;
  x0 += x1; x1 = rotl32(x1, 29); x1 ^= x0;
  x0 += x1; x1 = rotl32(x1, 16); x1 ^= x0;
  x0 += x1; x1 = rotl32(x1, 24); x1 ^= x0;
  x0 += ks2; x1 += k0 + 2u;
  x0 += x1; x1 = rotl32(x1, 13); x1 ^= x0;
  x0 += x1; x1 = rotl32(x1, 15); x1 ^= x0;
  x0 += x1; x1 = rotl32(x1, 26); x1 ^= x0;
  x0 += x1; x1 = rotl32(x1,  6); x1 ^= x0;
  x0 += k0; x1 += k1 + 3u;
  x0 += x1; x1 = rotl32(x1, 17); x1 ^= x0;
  x0 += x1; x1 = rotl32(x1, 29); x1 ^= x0;
  x0 += x1; x1 = rotl32(x1, 16); x1 ^= x0;
  x0 += x1; x1 = rotl32(x1, 24); x1 ^= x0;
  x0 += k1; x1 += ks2 + 4u;
  x0 += x1; x1 = rotl32(x1, 13); x1 ^= x0;
  x0 += x1; x1 = rotl32(x1, 15); x1 ^= x0;
  x0 += x1; x1 = rotl32(x1, 26); x1 ^= x0;
  x0 += x1; x1 = rotl32(x1,  6); x1 ^= x0;
  x0 += ks2; x1 += k0 + 5u;
  return {x0, x1};
}

// partitionable threefry (validated bit-exact in R1-R3)
__device__ __forceinline__ uint32_t rbits32(uint32_t k0, uint32_t k1, uint32_t m) {
  U2 r = tf2x32(k0, k1, 0u, m);
  return r.a ^ r.b;
}
__device__ __forceinline__ U2 split_key(uint32_t k0, uint32_t k1, uint32_t idx) {
  return tf2x32(k0, k1, 0u, idx);
}

// gumbel from raw bits — expression identical to R1-R3 (bit-exact g)
__device__ __forceinline__ float gumbel_from(uint32_t bits) {
  float u = __uint_as_float(0x3f800000u | (bits >> 9)) - 1.0f;
  u = fmaxf(u + 1.17549435e-38f, 1.17549435e-38f);
  return -logf(-logf(u));
}

__device__ __forceinline__ float bpermf(int byteidx, float v) {
  return __int_as_float(__builtin_amdgcn_ds_bpermute(byteidx, __float_as_int(v)));
}

// ============================================================================
// Kernel A: blocks 0..19 tbl | 20,21 T0 (col sums) | 22,23 U0 (row sums) |
//           24..151 C = W z^T
// ============================================================================
__global__ __launch_bounds__(256)
void pre_kernel(const float* __restrict__ A, const float* __restrict__ W,
                const float* __restrict__ z, uint32_t* __restrict__ wsu,
                float* __restrict__ wsf) {
  const int bid = blockIdx.x, tid = threadIdx.x;
  uint32_t* tbl = wsu + WS_TBL;
  float* T0 = wsf + WS_T0;
  float* U0 = wsf + WS_U0;
  float* C  = wsf + WS_C;
  __shared__ float4 zs4[128];

  if (bid < MIX_TIME) {
    if (tid < 64) {
      const uint32_t t    = (uint32_t)bid;
      const uint32_t lane = (uint32_t)tid;
      const U2 K   = split_key(0u, 1u, t);
      const U2 ki  = split_key(K.a, K.b, 0u);
      const U2 ks  = split_key(K.a, K.b, 1u);
      const U2 sub = split_key(ki.a, ki.b, 1u);

      uint32_t k1 = 0xFFFFFFFFu, m1 = 0xFFFFFFFFu;
      uint32_t k2 = 0xFFFFFFFFu, m2 = 0xFFFFFFFFu;
      #pragma unroll
      for (int p = 0; p < 8; ++p) {
        const uint32_t m   = lane + 64u * (uint32_t)p;
        const uint32_t key = rbits32(sub.a, sub.b, m);
        const bool lt1 = (key < k1) || (key == k1 && m < m1);
        const bool lt2 = (key < k2) || (key == k2 && m < m2);
        if (lt1)      { k2 = k1; m2 = m1; k1 = key; m1 = m; }
        else if (lt2) { k2 = key; m2 = m; }
      }
      #pragma unroll
      for (int msk = 1; msk < 64; msk <<= 1) {
        const uint32_t ok1 = __shfl_xor((int)k1, msk, 64);
        const uint32_t om1 = __shfl_xor((int)m1, msk, 64);
        const uint32_t ok2 = __shfl_xor((int)k2, msk, 64);
        const uint32_t om2 = __shfl_xor((int)m2, msk, 64);
        const bool oless = (ok1 < k1) || (ok1 == k1 && om1 < m1);
        if (oless) {
          const bool l2 = (k1 < ok2) || (k1 == ok2 && m1 < om2);
          const uint32_t nk2 = l2 ? k1 : ok2, nm2 = l2 ? m1 : om2;
          k1 = ok1; m1 = om1; k2 = nk2; m2 = nm2;
        } else {
          const bool l2 = (ok1 < k2) || (ok1 == k2 && om1 < m2);
          if (l2) { k2 = ok1; m2 = om1; }
        }
      }
      if (lane == 0) {
        tbl[4u * t + 0u] = m1;
        tbl[4u * t + 1u] = m2;
        tbl[4u * t + 2u] = ks.a;
        tbl[4u * t + 3u] = ks.b;
      }
    }
    return;
  }

  if (bid < MIX_TIME + 2) {          // T0[e] = sum_{d<64} A[d,e]
    const int e = (bid - MIX_TIME) * 256 + tid;
    float s = 0.f;
    #pragma unroll 1
    for (int d = 0; d < 64; ++d) s += A[(size_t)d * DDIM + e];
    T0[e] = s;
    return;
  }

  if (bid < MIX_TIME + 4) {          // U0[d] = sum_{e<64} A[d,e] (ascending)
    const int d = (bid - MIX_TIME - 2) * 256 + tid;
    const float4* Ar = reinterpret_cast<const float4*>(A + (size_t)d * DDIM);
    float s = 0.f;
    #pragma unroll
    for (int k = 0; k < 16; ++k) {
      const float4 v = Ar[k];
      s += v.x; s += v.y; s += v.z; s += v.w;
    }
    U0[d] = s;
    return;
  }

  const int b = bid - (MIX_TIME + 4);
  if (tid < 128) zs4[tid] = reinterpret_cast<const float4*>(z + (size_t)b * DDIM)[tid];
  __syncthreads();
  #pragma unroll
  for (int rr = 0; rr < 2; ++rr) {
    const int d = tid + rr * 256;
    const float4* Wr = reinterpret_cast<const float4*>(W + (size_t)d * DDIM);
    float s = 0.f;
    #pragma unroll 4
    for (int k = 0; k < 128; ++k) {
      const float4 w = Wr[k], zz = zs4[k];
      s = fmaf(w.x, zz.x, s); s = fmaf(w.y, zz.y, s);
      s = fmaf(w.z, zz.z, s); s = fmaf(w.w, zz.w, s);
    }
    C[(size_t)b * DDIM + d] = s;
  }
}

// ============================================================================
// Kernel B (1 block): sc scalars, G/Gt 40x40, ct, Sz0, St0.
// ============================================================================
__global__ __launch_bounds__(256)
void scal_kernel(const float* __restrict__ A, uint32_t* __restrict__ wsu,
                 float* __restrict__ wsf) {
  const int tid = threadIdx.x;
  const uint32_t* tbl = wsu + WS_TBL;
  const float* T0 = wsf + WS_T0;
  const float* C  = wsf + WS_C;
  uint32_t* sc  = wsu + WS_SC;
  float*    ct  = wsf + WS_CT;
  float*    G   = wsf + WS_G;
  float*    Gt  = wsf + WS_GT;
  float*    Sz0 = wsf + WS_SZ0;
  float*    St0 = wsf + WS_ST0;

  if (tid < MIX_TIME) {
    const uint32_t i = tbl[4 * tid], j = tbl[4 * tid + 1];
    uint32_t* s = sc + 8 * tid;
    s[0] = i; s[1] = j;
    s[2] = __float_as_uint(A[(size_t)i * DDIM + i]);
    s[3] = __float_as_uint(A[(size_t)i * DDIM + j]);
    s[4] = __float_as_uint(A[(size_t)j * DDIM + i]);
    s[5] = __float_as_uint(A[(size_t)j * DDIM + j]);
    s[6] = 0u; s[7] = 0u;
  }
  if (tid == 20) {
    float s = 0.f;
    #pragma unroll 1
    for (int e = 0; e < 64; ++e) s += T0[e];
    St0[0] = s;
  }
  #pragma unroll 1
  for (int p = tid; p < 1600; p += 256) {
    const int r = p / 40, c = p % 40;
    const uint32_t cr = tbl[4 * (r >> 1) + (r & 1)];
    const uint32_t cc = tbl[4 * (c >> 1) + (c & 1)];
    G[p]  = A[(size_t)cr * DDIM + cc];
    Gt[p] = A[(size_t)cc * DDIM + cr];
  }
  #pragma unroll 1
  for (int p = tid; p < MIX_TIME * 128; p += 256) {
    const int t = p >> 7, b = p & 127;
    const uint32_t i = tbl[4 * t], j = tbl[4 * t + 1];
    ct[2 * p]     = C[(size_t)b * DDIM + i];
    ct[2 * p + 1] = C[(size_t)b * DDIM + j];
  }
  if (tid < 128) {
    float s = 0.f;
    #pragma unroll 1
    for (int e = 0; e < 64; ++e) s += C[(size_t)tid * DDIM + e];
    Sz0[tid] = s;
  }
}

// ============================================================================
// Kernel C: sampler. 2 chains/wave (32-lane halves). Lane t' (=tid&31) holds
// current T[i_t'], T[j_t'], U[i_t'], U[j_t'], c_i, c_j, x[i_t'], x[j_t'].
// Per step: 8 bpermute broadcasts + uniform algebra + argmax + lane-parallel
// future update from G/Gt in LDS. m16 = 16 output bits per lane.
// ============================================================================
__global__ __launch_bounds__(256)
void gibbs_g_kernel(const uint32_t* __restrict__ wsu,
                    const float* __restrict__ wsf,
                    float* __restrict__ out) {
  const int tid = threadIdx.x;
  const uint32_t* tbl = wsu + WS_TBL;
  const uint32_t* sc  = wsu + WS_SC;
  const float* T0  = wsf + WS_T0;
  const float* U0  = wsf + WS_U0;
  const float* ct  = wsf + WS_CT;
  const float* Gg  = wsf + WS_G;     // G then Gt, contiguous 3200 floats
  const float* Sz0 = wsf + WS_SZ0;
  const float* St0 = wsf + WS_ST0;

  __shared__ __align__(16) float gg[3200];   // [0,1600)=G, [1600,3200)=Gt
  #pragma unroll
  for (int k = 0; k < 4; ++k) {
    const int idx = tid + k * 256;
    if (idx < 800)
      reinterpret_cast<float4*>(gg)[idx] = reinterpret_cast<const float4*>(Gg)[idx];
  }
  __syncthreads();

  const int hl = tid & 31;                  // t' slot within half
  const int hb = (tid & 32) << 2;           // bpermute byte base of this half
  const int c4 = tid & 3;
  const int gb = hb + (c4 << 2);            // gumbel bpermute base
  const uint32_t chain = (uint32_t)blockIdx.x * 8u
                       + (uint32_t)((tid >> 6) * 2) + (uint32_t)((tid >> 5) & 1);
  const uint32_t b = chain & 127u;
  const float fa  = (float)((c4 >> 1) & 1);
  const float fb  = (float)(c4 & 1);
  const float fab = fa * fb;

  // ---- per-lane step data (lanes t' >= 20 clamped; never read) ----
  const int tc = (hl < MIX_TIME) ? hl : 0;
  const uint32_t iil = tbl[4 * tc], jjl = tbl[4 * tc + 1];
  float fTi = T0[iil], fTj = T0[jjl];
  float fUi = U0[iil], fUj = U0[jjl];
  const float2 cc2 = *reinterpret_cast<const float2*>(ct + 2 * (tc * 128 + (int)b));
  float cil = cc2.x, cjl = cc2.y;
  float xil = (iil < 64u) ? 1.f : 0.f;
  float xjl = (jjl < 64u) ? 1.f : 0.f;
  float St = St0[0];
  float Sz = Sz0[b];
  uint32_t m16 = (hl < 4) ? 0xFFFFu : 0u;   // x0: elements [16hl,16hl+16) < 64

  // ---- batched gumbels: reg r holds flat = 32r + hl, flat = 4t + c ----
  float g0, g1, g2;
  {
    const int f0 = hl;            // t 0..7
    g0 = gumbel_from(rbits32(tbl[4 * (f0 >> 2) + 2], tbl[4 * (f0 >> 2) + 3],
                             chain * 4u + (uint32_t)(f0 & 3)));
    const int f1 = 32 + hl;       // t 8..15
    g1 = gumbel_from(rbits32(tbl[4 * (f1 >> 2) + 2], tbl[4 * (f1 >> 2) + 3],
                             chain * 4u + (uint32_t)(f1 & 3)));
    const int f2 = (64 + hl < 80) ? (64 + hl) : 79;   // t 16..19 (hl<16)
    g2 = gumbel_from(rbits32(tbl[4 * (f2 >> 2) + 2], tbl[4 * (f2 >> 2) + 3],
                             chain * 4u + (uint32_t)(f2 & 3)));
  }

  #pragma unroll
  for (int t = 0; t < MIX_TIME; ++t) {
    // globally-uniform scalars -> SGPR loads
    const uint32_t ii = sc[8 * t], jj = sc[8 * t + 1];
    const float Aii = __uint_as_float(sc[8 * t + 2]);
    const float Aij = __uint_as_float(sc[8 * t + 3]);
    const float Aji = __uint_as_float(sc[8 * t + 4]);
    const float Ajj = __uint_as_float(sc[8 * t + 5]);

    // per-half broadcasts from lane t
    const int sb = hb + 4 * t;
    const float Ti  = bpermf(sb, fTi), Tj  = bpermf(sb, fTj);
    const float Ui  = bpermf(sb, fUi), Uj  = bpermf(sb, fUj);
    const float cib = bpermf(sb, cil), cjb = bpermf(sb, cjl);
    const float xi  = bpermf(sb, xil), xj  = bpermf(sb, xjl);

    const float si   = Ui - xi * Aii - xj * Aij;
    const float sj   = Uj - xi * Aji - xj * Ajj;
    const float sTR  = St - xi * Ti - xj * Tj;
    const float szR  = Sz - xi * cib - xj * cjb;
    const float QR   = sTR - xi * si - xj * sj;
    const float coli = Ti - xi * Aii - xj * Aji;
    const float colj = Tj - xi * Aij - xj * Ajj;
    const float base = QR + szR;
    const float gi   = si + coli + Aii + cib;
    const float gj   = sj + colj + Ajj + cjb;
    const float gij  = Aij + Aji;

    const float gsel = (t < 8) ? g0 : (t < 16) ? g1 : g2;
    const float gv   = bpermf(gb + (((4 * t) & 31) << 2), gsel);
    const float v    = gv + (base + fa * gi + fb * gj + fab * gij);

    // first-max argmax over 4 combos (4-lane butterfly; same in both halves' groups)
    float bv = v; int bestc = c4;
    #pragma unroll
    for (int msk = 1; msk < 4; msk <<= 1) {
      const float ov = __shfl_xor(bv, msk, 64);
      const int   oc = __shfl_xor(bestc, msk, 64);
      if (ov > bv || (ov == bv && oc < bestc)) { bv = ov; bestc = oc; }
    }

    const int ian = (bestc >> 1) & 1, ibn = bestc & 1;
    const float fan = (float)ian, fbn = (float)ibn;
    const float fdi = fan - xi, fdj = fbn - xj;

    St = St + fdi * Ti + fdj * Tj
            + fdi * (si + fan * Aii + fbn * Aij)
            + fdj * (sj + fan * Aji + fbn * Ajj);
    Sz = Sz + fdi * cib + fdj * cjb;

    // lane-parallel future-state updates (exact no-op when fdi=fdj=0)
    const float2 ga = *reinterpret_cast<const float2*>(&gg[80 * t + 2 * hl]);
    const float2 gB = *reinterpret_cast<const float2*>(&gg[80 * t + 40 + 2 * hl]);
    const float2 gc = *reinterpret_cast<const float2*>(&gg[1600 + 80 * t + 2 * hl]);
    const float2 gd = *reinterpret_cast<const float2*>(&gg[1600 + 80 * t + 40 + 2 * hl]);
    fTi = fmaf(fdi, ga.x, fmaf(fdj, gB.x, fTi));
    fTj = fmaf(fdi, ga.y, fmaf(fdj, gB.y, fTj));
    fUi = fmaf(fdi, gc.x, fmaf(fdj, gd.x, fUi));
    fUj = fmaf(fdi, gc.y, fmaf(fdj, gd.y, fUj));

    // per-lane x maintenance (coords can repeat across steps)
    xil = (iil == ii) ? fan : (iil == jj) ? fbn : xil;
    xjl = (jjl == ii) ? fan : (jjl == jj) ? fbn : xjl;

    // output mask maintenance
    const uint32_t ibit = 1u << (ii & 15u);
    const uint32_t nmi  = (m16 & ~ibit) | ((uint32_t)(-ian) & ibit);
    m16 = ((ii >> 4) == (uint32_t)hl) ? nmi : m16;
    const uint32_t jbit = 1u << (jj & 15u);
    const uint32_t nmj  = (m16 & ~jbit) | ((uint32_t)(-ibn) & jbit);
    m16 = ((jj >> 4) == (uint32_t)hl) ? nmj : m16;
  }

  // ---- output: lane hl writes elements [16hl, 16hl+16) of its chain ----
  float* op = out + (size_t)chain * DDIM + (size_t)(hl * 16);
  #pragma unroll
  for (int k = 0; k < 4; ++k) {
    float4 o;
    o.x = (float)((m16 >> (4 * k + 0)) & 1u);
    o.y = (float)((m16 >> (4 * k + 1)) & 1u);
    o.z = (float)((m16 >> (4 * k + 2)) & 1u);
    o.w = (float)((m16 >> (4 * k + 3)) & 1u);
    *reinterpret_cast<float4*>(op + 4 * k) = o;
  }
}

extern "C" void kernel_launch(void* const* d_in, const int* in_sizes, int n_in,
                              void* d_out, int out_size, void* d_ws, size_t ws_size,
                              hipStream_t stream) {
  const float* z = (const float*)d_in[0];   // (128, 512)
  const float* A = (const float*)d_in[1];   // (512, 512)
  const float* W = (const float*)d_in[2];   // (512, 512)
  float* out = (float*)d_out;               // (128, 128, 512)
  uint32_t* wsu = (uint32_t*)d_ws;
  float*    wsf = (float*)d_ws;

  hipLaunchKernelGGL(pre_kernel, dim3(MIX_TIME + 4 + 128), dim3(256), 0, stream,
                     A, W, z, wsu, wsf);
  hipLaunchKernelGGL(scal_kernel, dim3(1), dim3(256), 0, stream, A, wsu, wsf);
  hipLaunchKernelGGL(gibbs_g_kernel, dim3(NCHAIN / 8), dim3(256), 0, stream,
                     wsu, wsf, out);
}

// Round 5
// 82.091 us; speedup vs baseline: 60.8156x; 1.1834x over previous
//
#include <hip/hip_runtime.h>
#include <stdint.h>

// ============================================================================
// Bit-exact JAX Gibbs sampler — R5: 8 chains/wave + 2-kernel pipeline.
// All arithmetic (threefry, gumbel, logit algebra, St/Sz/T/U update orders,
// T0/U0/St0/Sz0 summation orders) is kept BIT-IDENTICAL to R4 (absmax 0.0).
// Only the lane/kernel packing changes.
// ============================================================================
#define MIX_TIME 20
#define NCHAIN   16384   // S*B = 128*128
#define DDIM     512

// ws layout in 4-byte units
#define WS_TBL 0        // 80  (pad 128)
#define WS_SC  128      // 160
#define WS_T0  288      // 512
#define WS_U0  800      // 512
#define WS_G   1312     // 1600
#define WS_GT  2912     // 1600
#define WS_ST0 4512     // 1 (pad 32)
#define WS_SZ0 4544     // 128
#define WS_C   4672     // 65536

struct U2 { uint32_t a, b; };

__device__ __forceinline__ uint32_t rotl32(uint32_t v, int r) {
  return (v << r) | (v >> (32 - r));
}

// Threefry-2x32, 20 rounds (JAX prng.py / Random123).
__device__ __forceinline__ U2 tf2x32(uint32_t k0, uint32_t k1, uint32_t x0, uint32_t x1) {
  const uint32_t ks2 = k0 ^ k1 ^ 0x1BD11BDAu;
  x0 += k0; x1 += k1;
  x0 += x1; x1 = rotl32(x1, 13); x1 ^= x0;
  x0 += x1; x1 = rotl32(x1, 15); x1 ^= x0;
  x0 += x1; x1 = rotl32(x1, 26); x1 ^= x0;
  x0 += x1; x1 = rotl32(x1,  6); x1 ^= x0;
  x0 += k1; x1 += ks2 + 1u;
  x0 += x1; x1 = rotl32(x1, 17); x1 ^= x0;
  x0 += x1; x1 = rotl32(x1, 29); x1 ^= x0;
  x0 += x1; x1 = rotl32(x1, 16); x1 ^= x0;
  x0 += x1; x1 = rotl32(x1, 24); x1 ^= x0;
  x0 += ks2; x1 += k0 + 2u;
  x0 += x1; x1 = rotl32(x1, 13); x1 ^= x0;
  x0 += x1; x1 = rotl32(x1, 15); x1 ^= x0;
  x0 += x1; x1 = rotl32(x1, 26); x1 ^= x0;
  x0 += x1; x1 = rotl32(x1,  6); x1 ^= x0;
  x0 += k0; x1 += k1 + 3u;
  x0 += x1; x1 = rotl32(x1, 17); x1 ^= x0;
  x0 += x1; x1 = rotl32(x1, 29); x1 ^= x0;
  x0 += x1; x1 = rotl32(x1, 16); x1 ^= x0;
  x0 += x1; x1 = rotl32(x1, 24); x1 ^= x0;
  x0 += k1; x1 += ks2 + 4u;
  x0 += x1; x1 = rotl32(x1, 13); x1 ^= x0;
  x0 += x1; x1 = rotl32(x1, 15); x1 ^= x0;
  x0 += x1; x1 = rotl32(x1, 26); x1 ^= x0;
  x0 += x1; x1 = rotl32(x1,  6); x1 ^= x0;
  x0 += ks2; x1 += k0 + 5u;
  return {x0, x1};
}

// partitionable threefry (validated bit-exact in R1-R4)
__device__ __forceinline__ uint32_t rbits32(uint32_t k0, uint32_t k1, uint32_t m) {
  U2 r = tf2x32(k0, k1, 0u, m);
  return r.a ^ r.b;
}
__device__ __forceinline__ U2 split_key(uint32_t k0, uint32_t k1, uint32_t idx) {
  return tf2x32(k0, k1, 0u, idx);
}

// gumbel from raw bits — expression identical to R1-R4 (bit-exact g)
__device__ __forceinline__ float gumbel_from(uint32_t bits) {
  float u = __uint_as_float(0x3f800000u | (bits >> 9)) - 1.0f;
  u = fmaxf(u + 1.17549435e-38f, 1.17549435e-38f);
  return -logf(-logf(u));
}

__device__ __forceinline__ float bpermf(int byteidx, float v) {
  return __int_as_float(__builtin_amdgcn_ds_bpermute(byteidx, __float_as_int(v)));
}

// ============================================================================
// Kernel A: bid 0: step table (4 waves x 5 sorts) + sc + G/Gt gathers
//           bid 1,2: T0 (+St0 in bid 1) | bid 3,4: U0 | bid 5..132: C (+Sz0)
// ============================================================================
__global__ __launch_bounds__(256)
void pre_kernel(const float* __restrict__ A, const float* __restrict__ W,
                const float* __restrict__ z, uint32_t* __restrict__ wsu,
                float* __restrict__ wsf) {
  const int bid = blockIdx.x, tid = threadIdx.x;
  uint32_t* tbl = wsu + WS_TBL;
  uint32_t* sc  = wsu + WS_SC;
  float* T0  = wsf + WS_T0;
  float* U0  = wsf + WS_U0;
  float* G   = wsf + WS_G;
  float* Gt  = wsf + WS_GT;
  float* St0 = wsf + WS_ST0;
  float* Sz0 = wsf + WS_SZ0;
  float* C   = wsf + WS_C;

  __shared__ uint32_t tblL[4 * MIX_TIME];
  __shared__ float    sred[64];
  __shared__ float4   zs4[128];

  if (bid == 0) {
    // ---- phase 1: each of 4 waves derives 5 steps (bit-identical sort) ----
    const int wv = tid >> 6;
    const uint32_t lane = (uint32_t)(tid & 63);
    #pragma unroll 1
    for (int k5 = 0; k5 < 5; ++k5) {
      const uint32_t t = (uint32_t)(wv * 5 + k5);
      const U2 K   = split_key(0u, 1u, t);
      const U2 ki  = split_key(K.a, K.b, 0u);
      const U2 ks  = split_key(K.a, K.b, 1u);
      const U2 sub = split_key(ki.a, ki.b, 1u);

      uint32_t k1 = 0xFFFFFFFFu, m1 = 0xFFFFFFFFu;
      uint32_t k2 = 0xFFFFFFFFu, m2 = 0xFFFFFFFFu;
      #pragma unroll
      for (int p = 0; p < 8; ++p) {
        const uint32_t m   = lane + 64u * (uint32_t)p;
        const uint32_t key = rbits32(sub.a, sub.b, m);
        const bool lt1 = (key < k1) || (key == k1 && m < m1);
        const bool lt2 = (key < k2) || (key == k2 && m < m2);
        if (lt1)      { k2 = k1; m2 = m1; k1 = key; m1 = m; }
        else if (lt2) { k2 = key; m2 = m; }
      }
      #pragma unroll
      for (int msk = 1; msk < 64; msk <<= 1) {
        const uint32_t ok1 = __shfl_xor((int)k1, msk, 64);
        const uint32_t om1 = __shfl_xor((int)m1, msk, 64);
        const uint32_t ok2 = __shfl_xor((int)k2, msk, 64);
        const uint32_t om2 = __shfl_xor((int)m2, msk, 64);
        const bool oless = (ok1 < k1) || (ok1 == k1 && om1 < m1);
        if (oless) {
          const bool l2 = (k1 < ok2) || (k1 == ok2 && m1 < om2);
          const uint32_t nk2 = l2 ? k1 : ok2, nm2 = l2 ? m1 : om2;
          k1 = ok1; m1 = om1; k2 = nk2; m2 = nm2;
        } else {
          const bool l2 = (ok1 < k2) || (ok1 == k2 && om1 < m2);
          if (l2) { k2 = ok1; m2 = om1; }
        }
      }
      if (lane == 0) {
        tbl[4u * t + 0u] = m1;  tblL[4u * t + 0u] = m1;
        tbl[4u * t + 1u] = m2;  tblL[4u * t + 1u] = m2;
        tbl[4u * t + 2u] = ks.a; tblL[4u * t + 2u] = ks.a;
        tbl[4u * t + 3u] = ks.b; tblL[4u * t + 3u] = ks.b;
      }
    }
    __syncthreads();
    // ---- phase 2: sc + G/Gt gathers from A ----
    if (tid < MIX_TIME) {
      const uint32_t i = tblL[4 * tid], j = tblL[4 * tid + 1];
      uint32_t* s = sc + 8 * tid;
      s[0] = i; s[1] = j;
      s[2] = __float_as_uint(A[(size_t)i * DDIM + i]);
      s[3] = __float_as_uint(A[(size_t)i * DDIM + j]);
      s[4] = __float_as_uint(A[(size_t)j * DDIM + i]);
      s[5] = __float_as_uint(A[(size_t)j * DDIM + j]);
      s[6] = 0u; s[7] = 0u;
    }
    #pragma unroll 1
    for (int p = tid; p < 1600; p += 256) {
      const int r = p / 40, c = p % 40;
      const uint32_t cr = tblL[4 * (r >> 1) + (r & 1)];
      const uint32_t cc = tblL[4 * (c >> 1) + (c & 1)];
      G[p]  = A[(size_t)cr * DDIM + cc];
      Gt[p] = A[(size_t)cc * DDIM + cr];
    }
    return;
  }

  if (bid <= 2) {                    // T0[e] = sum_{d<64} A[d,e] (+St0)
    const int e = (bid - 1) * 256 + tid;
    float s = 0.f;
    #pragma unroll 1
    for (int d = 0; d < 64; ++d) s += A[(size_t)d * DDIM + e];
    T0[e] = s;
    if (bid == 1) {
      if (tid < 64) sred[tid] = s;
      __syncthreads();
      if (tid == 0) {
        float q = 0.f;
        #pragma unroll 1
        for (int e2 = 0; e2 < 64; ++e2) q += sred[e2];
        St0[0] = q;
      }
    }
    return;
  }

  if (bid <= 4) {                    // U0[d] = sum_{e<64} A[d,e]
    const int d = (bid - 3) * 256 + tid;
    const float4* Ar = reinterpret_cast<const float4*>(A + (size_t)d * DDIM);
    float s = 0.f;
    #pragma unroll
    for (int k = 0; k < 16; ++k) {
      const float4 v = Ar[k];
      s += v.x; s += v.y; s += v.z; s += v.w;
    }
    U0[d] = s;
    return;
  }

  // ---- C[b][d] = sum_k W[d,k] z[b,k]  (+Sz0[b]) ----
  const int b = bid - 5;
  if (tid < 128) zs4[tid] = reinterpret_cast<const float4*>(z + (size_t)b * DDIM)[tid];
  __syncthreads();
  float s_keep = 0.f;
  #pragma unroll
  for (int rr = 0; rr < 2; ++rr) {
    const int d = tid + rr * 256;
    const float4* Wr = reinterpret_cast<const float4*>(W + (size_t)d * DDIM);
    float s = 0.f;
    #pragma unroll 4
    for (int k = 0; k < 128; ++k) {
      const float4 w = Wr[k], zz = zs4[k];
      s = fmaf(w.x, zz.x, s); s = fmaf(w.y, zz.y, s);
      s = fmaf(w.z, zz.z, s); s = fmaf(w.w, zz.w, s);
    }
    C[(size_t)b * DDIM + d] = s;
    if (rr == 0) s_keep = s;
  }
  if (tid < 64) sred[tid] = s_keep;
  __syncthreads();
  if (tid == 0) {
    float s = 0.f;
    #pragma unroll 1
    for (int e = 0; e < 64; ++e) s += sred[e];
    Sz0[b] = s;
  }
}

// ============================================================================
// Kernel B: sampler, 8 chains per wave.
//   algebra chain ql = l>>3 (8-lane groups; combos in aligned 4-lane subgroups)
//   state slot s = 8*t' + q: lane = s&63 (slot-chain qs = l&7), reg set = s>>6
//   gumbel flat f = 32*t + 4*q + c: lane = f&63, reg = f>>6
// ============================================================================
__global__ __launch_bounds__(256)
void gibbs8_kernel(const uint32_t* __restrict__ wsu,
                   const float* __restrict__ wsf,
                   float* __restrict__ out) {
  const int tid = threadIdx.x;
  const int l = tid & 63, wv = tid >> 6;
  const uint32_t* tbl = wsu + WS_TBL;
  const uint32_t* sc  = wsu + WS_SC;
  const float* T0w  = wsf + WS_T0;
  const float* U0w  = wsf + WS_U0;
  const float* Gg   = wsf + WS_G;    // G then Gt, contiguous 3200 floats
  const float* St0w = wsf + WS_ST0;
  const float* Sz0w = wsf + WS_SZ0;
  const float* Cw   = wsf + WS_C;

  __shared__ __align__(16) float gg[3200];
  #pragma unroll
  for (int k = 0; k < 4; ++k) {
    const int idx = tid + k * 256;
    if (idx < 800)
      reinterpret_cast<float4*>(gg)[idx] = reinterpret_cast<const float4*>(Gg)[idx];
  }

  const int ql = l >> 3, qs = l & 7, c4 = l & 3;
  const uint32_t chainbase = ((uint32_t)blockIdx.x * 4u + (uint32_t)wv) * 8u;
  const uint32_t chain_l = chainbase + (uint32_t)ql;
  const uint32_t b_l = chain_l & 127u;
  const uint32_t b_s = (chainbase + (uint32_t)qs) & 127u;
  const float fa  = (float)((c4 >> 1) & 1);
  const float fb  = (float)(c4 & 1);
  const float fab = fa * fb;

  // ---- state sets (values bit-identical to R4's per-slot init) ----
  float fTi[3], fTj[3], fUi[3], fUj[3], fci[3], fcj[3], fxi[3], fxj[3];
  uint32_t iiK[3], jjK[3];
  const float* ggb[3];
  #pragma unroll
  for (int k = 0; k < 3; ++k) {
    const int tp = (64 * k + l) >> 3;
    const int tc = (tp < MIX_TIME) ? tp : 0;
    const uint32_t i = sc[8 * tc], j = sc[8 * tc + 1];
    iiK[k] = i; jjK[k] = j;
    fTi[k] = T0w[i];  fTj[k] = T0w[j];
    fUi[k] = U0w[i];  fUj[k] = U0w[j];
    fci[k] = Cw[(size_t)b_s * DDIM + i];
    fcj[k] = Cw[(size_t)b_s * DDIM + j];
    fxi[k] = (i < 64u) ? 1.f : 0.f;
    fxj[k] = (j < 64u) ? 1.f : 0.f;
    ggb[k] = &gg[2 * tc];
  }
  float St = St0w[0];
  float Sz = Sz0w[b_l];
  uint32_t mlo = (qs == 0) ? 0xFFFFFFFFu : 0u;
  uint32_t mhi = mlo;

  // ---- batched gumbels: 10 regs x 64 lanes = 640 = 8 chains x 80 ----
  float garr[10];
  #pragma unroll
  for (int k = 0; k < 10; ++k) {
    const int f = 64 * k + l;
    const int t = f >> 5;
    const uint32_t qg = ((uint32_t)l & 31u) >> 2;
    const uint32_t m  = (chainbase + qg) * 4u + (uint32_t)(l & 3);
    garr[k] = gumbel_from(rbits32(tbl[4 * t + 2], tbl[4 * t + 3], m));
  }
  __syncthreads();

  const int gvbase = (4 * ql + c4) << 2;
  const int bq4    = ql << 2;

  #pragma unroll
  for (int t = 0; t < MIX_TIME; ++t) {
    const int kS   = t >> 3;
    const int bidx = (((8 * t) & 63) << 2) + bq4;
    const float Ti  = bpermf(bidx, fTi[kS]);
    const float Tj  = bpermf(bidx, fTj[kS]);
    const float Ui  = bpermf(bidx, fUi[kS]);
    const float Uj  = bpermf(bidx, fUj[kS]);
    const float cib = bpermf(bidx, fci[kS]);
    const float cjb = bpermf(bidx, fcj[kS]);
    const float xi  = bpermf(bidx, fxi[kS]);
    const float xj  = bpermf(bidx, fxj[kS]);
    const float gv  = bpermf(gvbase + ((t & 1) << 7), garr[t >> 1]);

    const uint32_t ii = sc[8 * t], jj = sc[8 * t + 1];
    const float Aii = __uint_as_float(sc[8 * t + 2]);
    const float Aij = __uint_as_float(sc[8 * t + 3]);
    const float Aji = __uint_as_float(sc[8 * t + 4]);
    const float Ajj = __uint_as_float(sc[8 * t + 5]);

    // ---- algebra (R4 verbatim) ----
    const float si   = Ui - xi * Aii - xj * Aij;
    const float sj   = Uj - xi * Aji - xj * Ajj;
    const float sTR  = St - xi * Ti - xj * Tj;
    const float szR  = Sz - xi * cib - xj * cjb;
    const float QR   = sTR - xi * si - xj * sj;
    const float coli = Ti - xi * Aii - xj * Aji;
    const float colj = Tj - xi * Aij - xj * Ajj;
    const float base = QR + szR;
    const float gi   = si + coli + Aii + cib;
    const float gj   = sj + colj + Ajj + cjb;
    const float gij  = Aij + Aji;
    const float v    = gv + (base + fa * gi + fb * gj + fab * gij);

    // ---- first-max argmax over 4 combos ----
    float bv = v; int bestc = c4;
    #pragma unroll
    for (int msk = 1; msk < 4; msk <<= 1) {
      const float ov = __shfl_xor(bv, msk, 64);
      const int   oc = __shfl_xor(bestc, msk, 64);
      if (ov > bv || (ov == bv && oc < bestc)) { bv = ov; bestc = oc; }
    }

    const int ian = (bestc >> 1) & 1, ibn = bestc & 1;
    const float fan = (float)ian, fbn = (float)ibn;
    const float fdi = fan - xi, fdj = fbn - xj;

    St = St + fdi * Ti + fdj * Tj
            + fdi * (si + fan * Aii + fbn * Aij)
            + fdj * (sj + fan * Aji + fbn * Ajj);
    Sz = Sz + fdi * cib + fdj * cjb;

    // ---- carry (fdi,fdj,bestc) of chain qs to slot-owner lanes ----
    const int pk  = ((int)fdi + 1) | (((int)fdj + 1) << 2) | (bestc << 4);
    const int pks = __builtin_amdgcn_ds_bpermute(qs << 5, pk);
    const float fdi_s = (float)((pks & 3) - 1);
    const float fdj_s = (float)(((pks >> 2) & 3) - 1);
    const float fan_s = (float)((pks >> 5) & 1);
    const float fbn_s = (float)((pks >> 4) & 1);

    // ---- slot updates (exact no-op when fdi_s=fdj_s=0) ----
    #pragma unroll
    for (int k = 0; k < 3; ++k) {
      const float2 ga = *reinterpret_cast<const float2*>(ggb[k] + 80 * t);
      const float2 gB = *reinterpret_cast<const float2*>(ggb[k] + 80 * t + 40);
      const float2 gc = *reinterpret_cast<const float2*>(ggb[k] + 1600 + 80 * t);
      const float2 gd = *reinterpret_cast<const float2*>(ggb[k] + 1600 + 80 * t + 40);
      fTi[k] = fmaf(fdi_s, ga.x, fmaf(fdj_s, gB.x, fTi[k]));
      fTj[k] = fmaf(fdi_s, ga.y, fmaf(fdj_s, gB.y, fTj[k]));
      fUi[k] = fmaf(fdi_s, gc.x, fmaf(fdj_s, gd.x, fUi[k]));
      fUj[k] = fmaf(fdi_s, gc.y, fmaf(fdj_s, gd.y, fUj[k]));
      fxi[k] = (iiK[k] == ii) ? fan_s : fxi[k];
      fxi[k] = (iiK[k] == jj) ? fbn_s : fxi[k];
      fxj[k] = (jjK[k] == ii) ? fan_s : fxj[k];
      fxj[k] = (jjK[k] == jj) ? fbn_s : fxj[k];
    }

    // ---- output-bit maintenance (chain ql; lane qs owns bits [64qs,64qs+64)) ----
    {
      const uint32_t ib = 1u << (ii & 31u);
      const uint32_t nv = (uint32_t)(-(int)ian) & ib;
      const bool own_i = ((uint32_t)qs == (ii >> 6));
      if ((ii >> 5) & 1u) { if (own_i) mhi = (mhi & ~ib) | nv; }
      else                { if (own_i) mlo = (mlo & ~ib) | nv; }
      const uint32_t jb = 1u << (jj & 31u);
      const uint32_t nj = (uint32_t)(-(int)ibn) & jb;
      const bool own_j = ((uint32_t)qs == (jj >> 6));
      if ((jj >> 5) & 1u) { if (own_j) mhi = (mhi & ~jb) | nj; }
      else                { if (own_j) mlo = (mlo & ~jb) | nj; }
    }
  }

  // ---- output: lane writes 64 elements of chain ql at offset 64*qs ----
  float* op = out + (size_t)chain_l * DDIM + (size_t)(qs * 64);
  #pragma unroll
  for (int g4 = 0; g4 < 16; ++g4) {
    const uint32_t w  = (g4 < 8) ? mlo : mhi;
    const int      sh = (g4 & 7) * 4;
    float4 o;
    o.x = (float)((w >> (sh + 0)) & 1u);
    o.y = (float)((w >> (sh + 1)) & 1u);
    o.z = (float)((w >> (sh + 2)) & 1u);
    o.w = (float)((w >> (sh + 3)) & 1u);
    *reinterpret_cast<float4*>(op + 4 * g4) = o;
  }
}

extern "C" void kernel_launch(void* const* d_in, const int* in_sizes, int n_in,
                              void* d_out, int out_size, void* d_ws, size_t ws_size,
                              hipStream_t stream) {
  const float* z = (const float*)d_in[0];   // (128, 512)
  const float* A = (const float*)d_in[1];   // (512, 512)
  const float* W = (const float*)d_in[2];   // (512, 512)
  float* out = (float*)d_out;               // (128, 128, 512)
  uint32_t* wsu = (uint32_t*)d_ws;
  float*    wsf = (float*)d_ws;

  hipLaunchKernelGGL(pre_kernel, dim3(5 + 128), dim3(256), 0, stream,
                     A, W, z, wsu, wsf);
  hipLaunchKernelGGL(gibbs8_kernel, dim3(NCHAIN / 32), dim3(256), 0, stream,
                     wsu, wsf, out);
}

// Round 7
// 51.630 us; speedup vs baseline: 96.6964x; 1.5900x over previous
//
#include <hip/hip_runtime.h>
#include <stdint.h>

// ============================================================================
// Bit-exact JAX Gibbs sampler — R6 resubmit (container died last round).
// R5 compute (bit-identical, absmax 0.0)
// + fully-coalesced output epilogue (fixes 4.8x write amplification)
// + 4x-parallel C-GEMM slabs in pre_kernel.
// ============================================================================
#define MIX_TIME 20
#define NCHAIN   16384   // S*B = 128*128
#define DDIM     512

// ws layout in 4-byte units
#define WS_TBL 0        // 80  (pad 128)
#define WS_SC  128      // 160
#define WS_T0  288      // 512
#define WS_U0  800      // 512
#define WS_G   1312     // 1600
#define WS_GT  2912     // 1600
#define WS_ST0 4512     // 1 (pad 32)
#define WS_SZ0 4544     // 128
#define WS_C   4672     // 65536

struct U2 { uint32_t a, b; };

__device__ __forceinline__ uint32_t rotl32(uint32_t v, int r) {
  return (v << r) | (v >> (32 - r));
}

// Threefry-2x32, 20 rounds (JAX prng.py / Random123).
__device__ __forceinline__ U2 tf2x32(uint32_t k0, uint32_t k1, uint32_t x0, uint32_t x1) {
  const uint32_t ks2 = k0 ^ k1 ^ 0x1BD11BDAu;
  x0 += k0; x1 += k1;
  x0 += x1; x1 = rotl32(x1, 13); x1 ^= x0;
  x0 += x1; x1 = rotl32(x1, 15); x1 ^= x0;
  x0 += x1; x1 = rotl32(x1, 26); x1 ^= x0;
  x0 += x1; x1 = rotl32(x1,  6); x1 ^= x0;
  x0 += k1; x1 += ks2 + 1u;
  x0 += x1; x1 = rotl32(x1, 17); x1 ^= x0;
  x0 += x1; x1 = rotl32(x1, 29); x1 ^= x0;
  x0 += x1; x1 = rotl32(x1, 16); x1 ^= x0;
  x0 += x1; x1 = rotl32(x1, 24); x1 ^= x0;
  x0 += ks2; x1 += k0 + 2u;
  x0 += x1; x1 = rotl32(x1, 13); x1 ^= x0;
  x0 += x1; x1 = rotl32(x1, 15); x1 ^= x0;
  x0 += x1; x1 = rotl32(x1, 26); x1 ^= x0;
  x0 += x1; x1 = rotl32(x1,  6); x1 ^= x0;
  x0 += k0; x1 += k1 + 3u;
  x0 += x1; x1 = rotl32(x1, 17); x1 ^= x0;
  x0 += x1; x1 = rotl32(x1, 29); x1 ^= x0;
  x0 += x1; x1 = rotl32(x1, 16); x1 ^= x0;
  x0 += x1; x1 = rotl32(x1, 24); x1 ^= x0;
  x0 += k1; x1 += ks2 + 4u;
  x0 += x1; x1 = rotl32(x1, 13); x1 ^= x0;
  x0 += x1; x1 = rotl32(x1, 15); x1 ^= x0;
  x0 += x1; x1 = rotl32(x1, 26); x1 ^= x0;
  x0 += x1; x1 = rotl32(x1,  6); x1 ^= x0;
  x0 += ks2; x1 += k0 + 5u;
  return {x0, x1};
}

// partitionable threefry (validated bit-exact in R1-R5)
__device__ __forceinline__ uint32_t rbits32(uint32_t k0, uint32_t k1, uint32_t m) {
  U2 r = tf2x32(k0, k1, 0u, m);
  return r.a ^ r.b;
}
__device__ __forceinline__ U2 split_key(uint32_t k0, uint32_t k1, uint32_t idx) {
  return tf2x32(k0, k1, 0u, idx);
}

// gumbel from raw bits — expression identical to R1-R5 (bit-exact g)
__device__ __forceinline__ float gumbel_from(uint32_t bits) {
  float u = __uint_as_float(0x3f800000u | (bits >> 9)) - 1.0f;
  u = fmaxf(u + 1.17549435e-38f, 1.17549435e-38f);
  return -logf(-logf(u));
}

__device__ __forceinline__ float bpermf(int byteidx, float v) {
  return __int_as_float(__builtin_amdgcn_ds_bpermute(byteidx, __float_as_int(v)));
}
__device__ __forceinline__ uint32_t bpermu(int byteidx, uint32_t v) {
  return (uint32_t)__builtin_amdgcn_ds_bpermute(byteidx, (int)v);
}

// ============================================================================
// Kernel A: bid 0: step table (4 waves x 5 sorts) + sc + G/Gt gathers
//           bid 1,2: T0 (+St0) | bid 3,4: U0 | bid 5..516: C slabs (+Sz0)
// ============================================================================
__global__ __launch_bounds__(256)
void pre_kernel(const float* __restrict__ A, const float* __restrict__ W,
                const float* __restrict__ z, uint32_t* __restrict__ wsu,
                float* __restrict__ wsf) {
  const int bid = blockIdx.x, tid = threadIdx.x;
  uint32_t* tbl = wsu + WS_TBL;
  uint32_t* sc  = wsu + WS_SC;
  float* T0  = wsf + WS_T0;
  float* U0  = wsf + WS_U0;
  float* G   = wsf + WS_G;
  float* Gt  = wsf + WS_GT;
  float* St0 = wsf + WS_ST0;
  float* Sz0 = wsf + WS_SZ0;
  float* C   = wsf + WS_C;

  __shared__ uint32_t tblL[4 * MIX_TIME];
  __shared__ float    sred[64];
  __shared__ float4   zs4[128];

  if (bid == 0) {
    // ---- phase 1: each of 4 waves derives 5 steps (bit-identical sort) ----
    const int wv = tid >> 6;
    const uint32_t lane = (uint32_t)(tid & 63);
    #pragma unroll 1
    for (int k5 = 0; k5 < 5; ++k5) {
      const uint32_t t = (uint32_t)(wv * 5 + k5);
      const U2 K   = split_key(0u, 1u, t);
      const U2 ki  = split_key(K.a, K.b, 0u);
      const U2 ks  = split_key(K.a, K.b, 1u);
      const U2 sub = split_key(ki.a, ki.b, 1u);

      uint32_t k1 = 0xFFFFFFFFu, m1 = 0xFFFFFFFFu;
      uint32_t k2 = 0xFFFFFFFFu, m2 = 0xFFFFFFFFu;
      #pragma unroll
      for (int p = 0; p < 8; ++p) {
        const uint32_t m   = lane + 64u * (uint32_t)p;
        const uint32_t key = rbits32(sub.a, sub.b, m);
        const bool lt1 = (key < k1) || (key == k1 && m < m1);
        const bool lt2 = (key < k2) || (key == k2 && m < m2);
        if (lt1)      { k2 = k1; m2 = m1; k1 = key; m1 = m; }
        else if (lt2) { k2 = key; m2 = m; }
      }
      #pragma unroll
      for (int msk = 1; msk < 64; msk <<= 1) {
        const uint32_t ok1 = __shfl_xor((int)k1, msk, 64);
        const uint32_t om1 = __shfl_xor((int)m1, msk, 64);
        const uint32_t ok2 = __shfl_xor((int)k2, msk, 64);
        const uint32_t om2 = __shfl_xor((int)m2, msk, 64);
        const bool oless = (ok1 < k1) || (ok1 == k1 && om1 < m1);
        if (oless) {
          const bool l2 = (k1 < ok2) || (k1 == ok2 && m1 < om2);
          const uint32_t nk2 = l2 ? k1 : ok2, nm2 = l2 ? m1 : om2;
          k1 = ok1; m1 = om1; k2 = nk2; m2 = nm2;
        } else {
          const bool l2 = (ok1 < k2) || (ok1 == k2 && om1 < m2);
          if (l2) { k2 = ok1; m2 = om1; }
        }
      }
      if (lane == 0) {
        tbl[4u * t + 0u] = m1;  tblL[4u * t + 0u] = m1;
        tbl[4u * t + 1u] = m2;  tblL[4u * t + 1u] = m2;
        tbl[4u * t + 2u] = ks.a; tblL[4u * t + 2u] = ks.a;
        tbl[4u * t + 3u] = ks.b; tblL[4u * t + 3u] = ks.b;
      }
    }
    __syncthreads();
    // ---- phase 2: sc + G/Gt gathers from A ----
    if (tid < MIX_TIME) {
      const uint32_t i = tblL[4 * tid], j = tblL[4 * tid + 1];
      uint32_t* s = sc + 8 * tid;
      s[0] = i; s[1] = j;
      s[2] = __float_as_uint(A[(size_t)i * DDIM + i]);
      s[3] = __float_as_uint(A[(size_t)i * DDIM + j]);
      s[4] = __float_as_uint(A[(size_t)j * DDIM + i]);
      s[5] = __float_as_uint(A[(size_t)j * DDIM + j]);
      s[6] = 0u; s[7] = 0u;
    }
    #pragma unroll 1
    for (int p = tid; p < 1600; p += 256) {
      const int r = p / 40, c = p % 40;
      const uint32_t cr = tblL[4 * (r >> 1) + (r & 1)];
      const uint32_t cc = tblL[4 * (c >> 1) + (c & 1)];
      G[p]  = A[(size_t)cr * DDIM + cc];
      Gt[p] = A[(size_t)cc * DDIM + cr];
    }
    return;
  }

  if (bid <= 2) {                    // T0[e] = sum_{d<64} A[d,e] (+St0)
    const int e = (bid - 1) * 256 + tid;
    float s = 0.f;
    #pragma unroll 1
    for (int d = 0; d < 64; ++d) s += A[(size_t)d * DDIM + e];
    T0[e] = s;
    if (bid == 1) {
      if (tid < 64) sred[tid] = s;
      __syncthreads();
      if (tid == 0) {
        float q = 0.f;
        #pragma unroll 1
        for (int e2 = 0; e2 < 64; ++e2) q += sred[e2];
        St0[0] = q;
      }
    }
    return;
  }

  if (bid <= 4) {                    // U0[d] = sum_{e<64} A[d,e]
    const int d = (bid - 3) * 256 + tid;
    const float4* Ar = reinterpret_cast<const float4*>(A + (size_t)d * DDIM);
    float s = 0.f;
    #pragma unroll
    for (int k = 0; k < 16; ++k) {
      const float4 v = Ar[k];
      s += v.x; s += v.y; s += v.z; s += v.w;
    }
    U0[d] = s;
    return;
  }

  // ---- C[b][d] = sum_k W[d,k] z[b,k], 4 slab-blocks per b (+Sz0 in slab 0) ----
  const int cb = bid - 5;            // 0..511
  const int b = cb >> 2, slab = cb & 3;
  if (tid < 128) zs4[tid] = reinterpret_cast<const float4*>(z + (size_t)b * DDIM)[tid];
  __syncthreads();
  if (tid < 128) {
    const int d = slab * 128 + tid;
    const float4* Wr = reinterpret_cast<const float4*>(W + (size_t)d * DDIM);
    float s = 0.f;
    #pragma unroll 4
    for (int k = 0; k < 128; ++k) {
      const float4 w = Wr[k], zz = zs4[k];
      s = fmaf(w.x, zz.x, s); s = fmaf(w.y, zz.y, s);
      s = fmaf(w.z, zz.z, s); s = fmaf(w.w, zz.w, s);
    }
    C[(size_t)b * DDIM + d] = s;
    if (slab == 0 && tid < 64) sred[tid] = s;
  }
  __syncthreads();
  if (slab == 0 && tid == 0) {
    float s = 0.f;
    #pragma unroll 1
    for (int e = 0; e < 64; ++e) s += sred[e];
    Sz0[b] = s;
  }
}

// ============================================================================
// Kernel B: sampler, 8 chains per wave (compute loop VERBATIM from R5).
// ============================================================================
__global__ __launch_bounds__(256)
void gibbs8_kernel(const uint32_t* __restrict__ wsu,
                   const float* __restrict__ wsf,
                   float* __restrict__ out) {
  const int tid = threadIdx.x;
  const int l = tid & 63, wv = tid >> 6;
  const uint32_t* tbl = wsu + WS_TBL;
  const uint32_t* sc  = wsu + WS_SC;
  const float* T0w  = wsf + WS_T0;
  const float* U0w  = wsf + WS_U0;
  const float* Gg   = wsf + WS_G;    // G then Gt, contiguous 3200 floats
  const float* St0w = wsf + WS_ST0;
  const float* Sz0w = wsf + WS_SZ0;
  const float* Cw   = wsf + WS_C;

  __shared__ __align__(16) float gg[3200];
  #pragma unroll
  for (int k = 0; k < 4; ++k) {
    const int idx = tid + k * 256;
    if (idx < 800)
      reinterpret_cast<float4*>(gg)[idx] = reinterpret_cast<const float4*>(Gg)[idx];
  }

  const int ql = l >> 3, qs = l & 7, c4 = l & 3;
  const uint32_t chainbase = ((uint32_t)blockIdx.x * 4u + (uint32_t)wv) * 8u;
  const uint32_t chain_l = chainbase + (uint32_t)ql;
  const uint32_t b_l = chain_l & 127u;
  const uint32_t b_s = (chainbase + (uint32_t)qs) & 127u;
  const float fa  = (float)((c4 >> 1) & 1);
  const float fb  = (float)(c4 & 1);
  const float fab = fa * fb;

  // ---- state sets (values bit-identical to R4/R5 per-slot init) ----
  float fTi[3], fTj[3], fUi[3], fUj[3], fci[3], fcj[3], fxi[3], fxj[3];
  uint32_t iiK[3], jjK[3];
  const float* ggb[3];
  #pragma unroll
  for (int k = 0; k < 3; ++k) {
    const int tp = (64 * k + l) >> 3;
    const int tc = (tp < MIX_TIME) ? tp : 0;
    const uint32_t i = sc[8 * tc], j = sc[8 * tc + 1];
    iiK[k] = i; jjK[k] = j;
    fTi[k] = T0w[i];  fTj[k] = T0w[j];
    fUi[k] = U0w[i];  fUj[k] = U0w[j];
    fci[k] = Cw[(size_t)b_s * DDIM + i];
    fcj[k] = Cw[(size_t)b_s * DDIM + j];
    fxi[k] = (i < 64u) ? 1.f : 0.f;
    fxj[k] = (j < 64u) ? 1.f : 0.f;
    ggb[k] = &gg[2 * tc];
  }
  float St = St0w[0];
  float Sz = Sz0w[b_l];
  uint32_t mlo = (qs == 0) ? 0xFFFFFFFFu : 0u;
  uint32_t mhi = mlo;

  // ---- batched gumbels: 10 regs x 64 lanes = 640 = 8 chains x 80 ----
  float garr[10];
  #pragma unroll
  for (int k = 0; k < 10; ++k) {
    const int f = 64 * k + l;
    const int t = f >> 5;
    const uint32_t qg = ((uint32_t)l & 31u) >> 2;
    const uint32_t m  = (chainbase + qg) * 4u + (uint32_t)(l & 3);
    garr[k] = gumbel_from(rbits32(tbl[4 * t + 2], tbl[4 * t + 3], m));
  }
  __syncthreads();

  const int gvbase = (4 * ql + c4) << 2;
  const int bq4    = ql << 2;

  #pragma unroll
  for (int t = 0; t < MIX_TIME; ++t) {
    const int kS   = t >> 3;
    const int bidx = (((8 * t) & 63) << 2) + bq4;
    const float Ti  = bpermf(bidx, fTi[kS]);
    const float Tj  = bpermf(bidx, fTj[kS]);
    const float Ui  = bpermf(bidx, fUi[kS]);
    const float Uj  = bpermf(bidx, fUj[kS]);
    const float cib = bpermf(bidx, fci[kS]);
    const float cjb = bpermf(bidx, fcj[kS]);
    const float xi  = bpermf(bidx, fxi[kS]);
    const float xj  = bpermf(bidx, fxj[kS]);
    const float gv  = bpermf(gvbase + ((t & 1) << 7), garr[t >> 1]);

    const uint32_t ii = sc[8 * t], jj = sc[8 * t + 1];
    const float Aii = __uint_as_float(sc[8 * t + 2]);
    const float Aij = __uint_as_float(sc[8 * t + 3]);
    const float Aji = __uint_as_float(sc[8 * t + 4]);
    const float Ajj = __uint_as_float(sc[8 * t + 5]);

    // ---- algebra (R4/R5 verbatim) ----
    const float si   = Ui - xi * Aii - xj * Aij;
    const float sj   = Uj - xi * Aji - xj * Ajj;
    const float sTR  = St - xi * Ti - xj * Tj;
    const float szR  = Sz - xi * cib - xj * cjb;
    const float QR   = sTR - xi * si - xj * sj;
    const float coli = Ti - xi * Aii - xj * Aji;
    const float colj = Tj - xi * Aij - xj * Ajj;
    const float base = QR + szR;
    const float gi   = si + coli + Aii + cib;
    const float gj   = sj + colj + Ajj + cjb;
    const float gij  = Aij + Aji;
    const float v    = gv + (base + fa * gi + fb * gj + fab * gij);

    // ---- first-max argmax over 4 combos ----
    float bv = v; int bestc = c4;
    #pragma unroll
    for (int msk = 1; msk < 4; msk <<= 1) {
      const float ov = __shfl_xor(bv, msk, 64);
      const int   oc = __shfl_xor(bestc, msk, 64);
      if (ov > bv || (ov == bv && oc < bestc)) { bv = ov; bestc = oc; }
    }

    const int ian = (bestc >> 1) & 1, ibn = bestc & 1;
    const float fan = (float)ian, fbn = (float)ibn;
    const float fdi = fan - xi, fdj = fbn - xj;

    St = St + fdi * Ti + fdj * Tj
            + fdi * (si + fan * Aii + fbn * Aij)
            + fdj * (sj + fan * Aji + fbn * Ajj);
    Sz = Sz + fdi * cib + fdj * cjb;

    // ---- carry (fdi,fdj,bestc) of chain qs to slot-owner lanes ----
    const int pk  = ((int)fdi + 1) | (((int)fdj + 1) << 2) | (bestc << 4);
    const int pks = __builtin_amdgcn_ds_bpermute(qs << 5, pk);
    const float fdi_s = (float)((pks & 3) - 1);
    const float fdj_s = (float)(((pks >> 2) & 3) - 1);
    const float fan_s = (float)((pks >> 5) & 1);
    const float fbn_s = (float)((pks >> 4) & 1);

    // ---- slot updates (exact no-op when fdi_s=fdj_s=0) ----
    #pragma unroll
    for (int k = 0; k < 3; ++k) {
      const float2 ga = *reinterpret_cast<const float2*>(ggb[k] + 80 * t);
      const float2 gB = *reinterpret_cast<const float2*>(ggb[k] + 80 * t + 40);
      const float2 gc = *reinterpret_cast<const float2*>(ggb[k] + 1600 + 80 * t);
      const float2 gd = *reinterpret_cast<const float2*>(ggb[k] + 1600 + 80 * t + 40);
      fTi[k] = fmaf(fdi_s, ga.x, fmaf(fdj_s, gB.x, fTi[k]));
      fTj[k] = fmaf(fdi_s, ga.y, fmaf(fdj_s, gB.y, fTj[k]));
      fUi[k] = fmaf(fdi_s, gc.x, fmaf(fdj_s, gd.x, fUi[k]));
      fUj[k] = fmaf(fdi_s, gc.y, fmaf(fdj_s, gd.y, fUj[k]));
      fxi[k] = (iiK[k] == ii) ? fan_s : fxi[k];
      fxi[k] = (iiK[k] == jj) ? fbn_s : fxi[k];
      fxj[k] = (jjK[k] == ii) ? fan_s : fxj[k];
      fxj[k] = (jjK[k] == jj) ? fbn_s : fxj[k];
    }

    // ---- output-bit maintenance (chain ql-independent; lane (q,qs) slots) ----
    {
      const uint32_t ib = 1u << (ii & 31u);
      const uint32_t nv = (uint32_t)(-(int)ian) & ib;
      const bool own_i = ((uint32_t)qs == (ii >> 6));
      if ((ii >> 5) & 1u) { if (own_i) mhi = (mhi & ~ib) | nv; }
      else                { if (own_i) mlo = (mlo & ~ib) | nv; }
      const uint32_t jb = 1u << (jj & 31u);
      const uint32_t nj = (uint32_t)(-(int)ibn) & jb;
      const bool own_j = ((uint32_t)qs == (jj >> 6));
      if ((jj >> 5) & 1u) { if (own_j) mhi = (mhi & ~jb) | nj; }
      else                { if (own_j) mlo = (mlo & ~jb) | nj; }
    }
  }

  // ---- output: fully-coalesced stores (bit-identical values, repacked) ----
  // Instruction g: lane l writes float4 index g*64+l of the wave's 8-chain
  // region -> 1 KB contiguous aligned per instruction, full 64B lines.
  // Owner of that nibble: lane 4g + (l>>4); bit offset 4*(l&15).
  {
    float* wavebase = out + (size_t)chainbase * DDIM;
    #pragma unroll
    for (int g = 0; g < 16; ++g) {
      const int bidx = 16 * g + ((l >> 4) << 2);
      const uint32_t wlo = bpermu(bidx, mlo);
      const uint32_t whi = bpermu(bidx, mhi);
      const uint32_t w   = ((l >> 3) & 1) ? whi : wlo;
      const uint32_t nib = (w >> (4 * (l & 7))) & 0xFu;
      float4 o;
      o.x = (float)( nib       & 1u);
      o.y = (float)((nib >> 1) & 1u);
      o.z = (float)((nib >> 2) & 1u);
      o.w = (float)((nib >> 3) & 1u);
      *reinterpret_cast<float4*>(
          wavebase + (size_t)((g >> 1) * 512 + (64 * (g & 1) + l) * 4)) = o;
    }
  }
}

extern "C" void kernel_launch(void* const* d_in, const int* in_sizes, int n_in,
                              void* d_out, int out_size, void* d_ws, size_t ws_size,
                              hipStream_t stream) {
  const float* z = (const float*)d_in[0];   // (128, 512)
  const float* A = (const float*)d_in[1];   // (512, 512)
  const float* W = (const float*)d_in[2];   // (512, 512)
  float* out = (float*)d_out;               // (128, 128, 512)
  uint32_t* wsu = (uint32_t*)d_ws;
  float*    wsf = (float*)d_ws;

  hipLaunchKernelGGL(pre_kernel, dim3(5 + 512), dim3(256), 0, stream,
                     A, W, z, wsu, wsf);
  hipLaunchKernelGGL(gibbs8_kernel, dim3(NCHAIN / 32), dim3(256), 0, stream,
                     wsu, wsf, out);
}